// Round 6
// baseline (1562.134 us; speedup 1.0000x reference)
//
#include <hip/hip_runtime.h>
#include <math.h>

typedef _Float16 f16;
typedef _Float16 f16x4 __attribute__((ext_vector_type(4)));
typedef _Float16 f16x8 __attribute__((ext_vector_type(8)));
typedef float f32x4 __attribute__((ext_vector_type(4)));

#define SEQ   2048
#define DIM   1024
#define NH    16
#define DH    64
#define NCOLS 6144
#define NHSD  (NH*SEQ*DH)   /* 2,097,152 elements per qkv sub-tensor */
#define MAXSPLIT 4
#define SPLITS_PER_HEAD 32  /* sum of S(I) over I=0..15 */

__device__ __forceinline__ int nsplits(int I) {
  return (I < 7) ? 1 : (I < 11) ? 2 : (I < 14) ? 3 : 4;
}

// ---------------- cast x (fp32 -> f16), vectorized x4 ----------------
__global__ __launch_bounds__(256) void k_cast_x(const float* __restrict__ x, f16* __restrict__ xh) {
  int i = (blockIdx.x * 256 + threadIdx.x) * 4;
  float4 v = *(const float4*)(x + i);
  f16x4 h; h[0] = (f16)v.x; h[1] = (f16)v.y; h[2] = (f16)v.z; h[3] = (f16)v.w;
  *(f16x4*)(xh + i) = h;
}

// ------------- transpose + cast: out[c][r] = (f16) in[r][c], in is R x C -------------
__global__ __launch_bounds__(256) void k_tcast(const float* __restrict__ in, f16* __restrict__ out,
                                               int R, int C) {
  __shared__ f16 t[64 * 66];
  int bc = blockIdx.x, br = blockIdx.y;
  for (int it = 0; it < 16; ++it) {
    int idx = it * 256 + threadIdx.x;
    int r = idx >> 6, c = idx & 63;
    t[r * 66 + c] = (f16)in[(size_t)(br * 64 + r) * C + bc * 64 + c];
  }
  __syncthreads();
  for (int it = 0; it < 16; ++it) {
    int idx = it * 256 + threadIdx.x;
    int oc = idx >> 6, orr = idx & 63;
    out[(size_t)(bc * 64 + oc) * R + br * 64 + orr] = t[orr * 66 + oc];
  }
}

// ---------------- qkv GEMM: xh[2048,1024] @ WqT[6144,1024]^T -> six packed tensors ----------------
__global__ __launch_bounds__(256) void k_gemm_qkv(const f16* __restrict__ A, const f16* __restrict__ B,
                                                  f16* __restrict__ q6) {
  __shared__ f16 sa[128 * 72];
  __shared__ f16 sb[128 * 72];
  int bx = blockIdx.x, by = blockIdx.y;
  int tid = threadIdx.x, w = tid >> 6, l = tid & 63, q = l >> 4, c = l & 15;
  f32x4 acc[2][8];
  const f32x4 zf = {0.f, 0.f, 0.f, 0.f};
  for (int i = 0; i < 2; ++i) for (int j = 0; j < 8; ++j) acc[i][j] = zf;

  for (int kt = 0; kt < DIM / 64; ++kt) {
    __syncthreads();
#pragma unroll
    for (int it = 0; it < 4; ++it) {
      int idx = it * 256 + tid; int r = idx >> 3, ch = idx & 7;
      *(float4*)(sa + r * 72 + ch * 8) = *(const float4*)(A + (size_t)(by * 128 + r) * DIM + kt * 64 + ch * 8);
      *(float4*)(sb + r * 72 + ch * 8) = *(const float4*)(B + (size_t)(bx * 128 + r) * DIM + kt * 64 + ch * 8);
    }
    __syncthreads();
#pragma unroll
    for (int ks = 0; ks < 2; ++ks) {
      f16x8 af[2], bf[8];
#pragma unroll
      for (int tr = 0; tr < 2; ++tr) af[tr] = *(const f16x8*)(sa + (w * 32 + tr * 16 + c) * 72 + ks * 32 + q * 8);
#pragma unroll
      for (int tc = 0; tc < 8; ++tc) bf[tc] = *(const f16x8*)(sb + (tc * 16 + c) * 72 + ks * 32 + q * 8);
#pragma unroll
      for (int tr = 0; tr < 2; ++tr)
#pragma unroll
        for (int tc = 0; tc < 8; ++tc)
          acc[tr][tc] = __builtin_amdgcn_mfma_f32_16x16x32_f16(af[tr], bf[tc], acc[tr][tc], 0, 0, 0);
    }
  }
  // epilogue: scatter into qu(0) ku(1) vu(2) qc(3) kc(4) vcT(5); scale qu,qc by dh^-0.5
#pragma unroll
  for (int tr = 0; tr < 2; ++tr)
#pragma unroll
    for (int tc = 0; tc < 8; ++tc)
#pragma unroll
      for (int r = 0; r < 4; ++r) {
        int row = by * 128 + w * 32 + tr * 16 + q * 4 + r;
        int col = bx * 128 + tc * 16 + c;
        float v = acc[tr][tc][r];
        int t = col >> 10, head = (col >> 6) & 15, dh = col & 63;
        if (t == 0 || t == 3) v *= 0.125f;
        if (t == 5) q6[(size_t)5 * NHSD + (size_t)(head * DH + dh) * SEQ + row] = (f16)v;
        else        q6[(size_t)t * NHSD + (size_t)(head * SEQ + row) * DH + dh] = (f16)v;
      }
}

// ---------------- split-K fused flash (R6: 512 threads, 8 waves x 16 rows) ----------------
// grid 512 = (head, I, split) XCD-swizzled: head = 2 heads per XCD -> 3 MB < 4 MB L2 (R5 win).
// R6: 8 waves of 16 rows each over the 128x128 tile. Per-lane accs halve (su 32, tacc 32, oacc 16
// VGPR) -> peak live ~120; __launch_bounds__(512,4) targets 128 VGPR = 2 blocks/CU = 4 waves/SIMD
// (R5 had 2 waves/SIMD at 256 VGPR; latency chain was exposed). bf loads chunked 4-at-a-time to
// keep the peak under 128. LDS unchanged: sa (t1/P, own-wave rows) + sb (lk, cross-wave).
__global__ __launch_bounds__(512, 4) void k_flash(const f16* __restrict__ q6,
                                                  f16* __restrict__ pO, float* __restrict__ pML) {
  __shared__ f16 sa[128 * 128];
  __shared__ f16 sb[128 * 128];
  int bid = blockIdx.x;
  int head = ((bid & 7) << 1) | ((bid >> 3) & 1);
  int rsub = bid >> 4;          // [0,32): split-block index within head
  // decode (I, s) from rsub
  int I = 0, s = 0;
  {
    int acc = 0;
    for (int ii = 0; ii < 16; ++ii) {
      int si = nsplits(ii);
      if (rsub >= acc && rsub < acc + si) { I = ii; s = rsub - acc; }
      acc += si;
    }
  }
  int S_ = nsplits(I);
  int C = (I + 1) * (I + 2) / 2;
  // midpoint equal-cost partition of K in [0,I]
  int K0 = 16, K1 = 0;
  {
    int p = 0;
    for (int K = 0; K <= I; ++K) {
      int cost = I - K + 1;
      int seg = ((2 * p + cost) * S_) / (2 * C);
      if (seg == s) { if (K < K0) K0 = K; K1 = K + 1; }
      p += cost;
    }
  }

  const f16* qu = q6 + (size_t)0 * NHSD + (size_t)head * SEQ * DH;   // pre-scaled by dh^-0.5
  const f16* ku = q6 + (size_t)1 * NHSD + (size_t)head * SEQ * DH;
  const f16* vu = q6 + (size_t)2 * NHSD + (size_t)head * SEQ * DH;
  const f16* qc = q6 + (size_t)3 * NHSD + (size_t)head * SEQ * DH;   // pre-scaled by dh^-0.5
  const f16* kc = q6 + (size_t)4 * NHSD + (size_t)head * SEQ * DH;
  const f16* vt = q6 + (size_t)5 * NHSD + (size_t)head * DH * SEQ;   // vc transposed [64][2048]
  int tid = threadIdx.x, w = tid >> 6, l = tid & 63, q = l >> 4, c = l & 15;
  int rw = w * 16;   // this wave's row base within the 128-row tile

  f32x4 su[8], tacc[8], oacc[4];
  float m_i[4], l_i[4];
  const f32x4 zf = {0.f, 0.f, 0.f, 0.f};
  for (int tv = 0; tv < 4; ++tv) oacc[tv] = zf;
  for (int r = 0; r < 4; ++r) { m_i[r] = -INFINITY; l_i[r] = 0.f; }

  for (int K = K0; K < K1; ++K) {
    for (int tc = 0; tc < 8; ++tc) su[tc] = zf;

    for (int J = K; J <= I; ++J) {
      __syncthreads();   // WAR: prior Su-MFMA reads of sb complete before restaging

      // ---- lookahead(K,J) tile: sigmoid(qu_s(K) @ ku(J)^T), keep j>k -> sb (own 16 rows) ----
#pragma unroll
      for (int tc = 0; tc < 8; ++tc) tacc[tc] = zf;
#pragma unroll
      for (int ks = 0; ks < 2; ++ks) {
        f16x8 aq = *(const f16x8*)(qu + (size_t)(K * 128 + rw + c) * DH + ks * 32 + q * 8);
#pragma unroll
        for (int th = 0; th < 2; ++th) {        // bf chunked x4 to cap VGPR peak
          f16x8 bf[4];
#pragma unroll
          for (int t4 = 0; t4 < 4; ++t4)
            bf[t4] = *(const f16x8*)(ku + (size_t)(J * 128 + (th * 4 + t4) * 16 + c) * DH + ks * 32 + q * 8);
#pragma unroll
          for (int t4 = 0; t4 < 4; ++t4)
            tacc[th * 4 + t4] = __builtin_amdgcn_mfma_f32_16x16x32_f16(aq, bf[t4], tacc[th * 4 + t4], 0, 0, 0);
        }
      }
#pragma unroll
      for (int tc = 0; tc < 8; ++tc)
#pragma unroll
        for (int r = 0; r < 4; ++r) {
          int row = rw + q * 4 + r;
          int col = tc * 16 + c;
          int kg = K * 128 + row, jg = J * 128 + col;
          float v = tacc[tc][r];
          f16 ov = (jg > kg) ? (f16)__builtin_amdgcn_rcpf(1.f + __expf(-v)) : (f16)(0.f);
          sb[(row << 7) + (((col >> 3) ^ (row & 15)) << 3) + (col & 7)] = ov;
        }

      // ---- term1(I,J) tile: qc_s(I) @ vu(J)^T, keep j<=i -> sa (own 16 rows) ----
#pragma unroll
      for (int tc = 0; tc < 8; ++tc) tacc[tc] = zf;
#pragma unroll
      for (int ks = 0; ks < 2; ++ks) {
        f16x8 aq = *(const f16x8*)(qc + (size_t)(I * 128 + rw + c) * DH + ks * 32 + q * 8);
#pragma unroll
        for (int th = 0; th < 2; ++th) {
          f16x8 bf[4];
#pragma unroll
          for (int t4 = 0; t4 < 4; ++t4)
            bf[t4] = *(const f16x8*)(vu + (size_t)(J * 128 + (th * 4 + t4) * 16 + c) * DH + ks * 32 + q * 8);
#pragma unroll
          for (int t4 = 0; t4 < 4; ++t4)
            tacc[th * 4 + t4] = __builtin_amdgcn_mfma_f32_16x16x32_f16(aq, bf[t4], tacc[th * 4 + t4], 0, 0, 0);
        }
      }
#pragma unroll
      for (int tc = 0; tc < 8; ++tc)
#pragma unroll
        for (int r = 0; r < 4; ++r) {
          int row = rw + q * 4 + r;
          int col = tc * 16 + c;
          int ig = I * 128 + row, jg = J * 128 + col;
          float v = tacc[tc][r];
          f16 ov = (jg <= ig) ? (f16)v : (f16)(0.f);
          sa[(row << 7) + (((col >> 3) ^ (row & 15)) << 3) + (col & 7)] = ov;
        }

      __syncthreads();   // RAW: sb (lk tile) visible to all waves

      // ---- Su += t1 @ lk^T over j (128 = 4 chunks of 32) ----
#pragma unroll
      for (int ks = 0; ks < 4; ++ks) {
        int ck = ks * 4 + q;
        f16x8 af = *(const f16x8*)(sa + ((rw + c) << 7) + ((ck ^ c) << 3));
        f16x8 bf[8];
#pragma unroll
        for (int tc = 0; tc < 8; ++tc)
          bf[tc] = *(const f16x8*)(sb + ((tc * 16 + c) << 7) + ((ck ^ c) << 3));
#pragma unroll
        for (int tc = 0; tc < 8; ++tc)
          su[tc] = __builtin_amdgcn_mfma_f32_16x16x32_f16(af, bf[tc], su[tc], 0, 0, 0);
      }
    }

    // scores = Sc - silu(Su): su = -silu(su), then MFMA adds Sc on top
#pragma unroll
    for (int tc = 0; tc < 8; ++tc)
#pragma unroll
      for (int r = 0; r < 4; ++r) {
        float v = su[tc][r];
        su[tc][r] = -v * __builtin_amdgcn_rcpf(1.f + __expf(-v));
      }
#pragma unroll
    for (int ks = 0; ks < 2; ++ks) {
      f16x8 aq = *(const f16x8*)(qc + (size_t)(I * 128 + rw + c) * DH + ks * 32 + q * 8);
#pragma unroll
      for (int th = 0; th < 2; ++th) {
        f16x8 bk[4];
#pragma unroll
        for (int t4 = 0; t4 < 4; ++t4)
          bk[t4] = *(const f16x8*)(kc + (size_t)(K * 128 + (th * 4 + t4) * 16 + c) * DH + ks * 32 + q * 8);
#pragma unroll
        for (int t4 = 0; t4 < 4; ++t4)
          su[th * 4 + t4] = __builtin_amdgcn_mfma_f32_16x16x32_f16(aq, bk[t4], su[th * 4 + t4], 0, 0, 0);
      }
    }
    if (K == I) {   // strict causal mask inside the diagonal block
#pragma unroll
      for (int tc = 0; tc < 8; ++tc)
#pragma unroll
        for (int r = 0; r < 4; ++r) {
          int rg = rw + q * 4 + r;
          int cg = tc * 16 + c;
          if (cg > rg) su[tc][r] = -INFINITY;
        }
    }
    // online softmax (row owned by 16 lanes sharing q; reduce across low-4 lane bits)
#pragma unroll
    for (int r = 0; r < 4; ++r) {
      float mx = su[0][r];
#pragma unroll
      for (int tc = 1; tc < 8; ++tc) mx = fmaxf(mx, su[tc][r]);
      mx = fmaxf(mx, __shfl_xor(mx, 1)); mx = fmaxf(mx, __shfl_xor(mx, 2));
      mx = fmaxf(mx, __shfl_xor(mx, 4)); mx = fmaxf(mx, __shfl_xor(mx, 8));
      float mnew  = fmaxf(m_i[r], mx);
      float alpha = __expf(m_i[r] - mnew);
      float ssum = 0.f;
#pragma unroll
      for (int tc = 0; tc < 8; ++tc) {
        float pp = __expf(su[tc][r] - mnew);
        su[tc][r] = pp;
        ssum += pp;
      }
      ssum += __shfl_xor(ssum, 1); ssum += __shfl_xor(ssum, 2);
      ssum += __shfl_xor(ssum, 4); ssum += __shfl_xor(ssum, 8);
      l_i[r] = l_i[r] * alpha + ssum;
      m_i[r] = mnew;
#pragma unroll
      for (int tv = 0; tv < 4; ++tv) oacc[tv][r] *= alpha;
    }
    // write P into sa (own 16 rows only -> no barrier; other waves never touch these rows)
#pragma unroll
    for (int tc = 0; tc < 8; ++tc)
#pragma unroll
      for (int r = 0; r < 4; ++r) {
        int row = rw + q * 4 + r;
        int col = tc * 16 + c;
        sa[(row << 7) + (((col >> 3) ^ (row & 15)) << 3) + (col & 7)] = (f16)su[tc][r];
      }
    // PV: A = P (own LDS rows), B = vcT straight from global (L2-resident)
#pragma unroll
    for (int ks = 0; ks < 4; ++ks) {
      int ck = ks * 4 + q;
      f16x8 af = *(const f16x8*)(sa + ((rw + c) << 7) + ((ck ^ c) << 3));
      f16x8 bv[4];
#pragma unroll
      for (int tv = 0; tv < 4; ++tv)
        bv[tv] = *(const f16x8*)(vt + (size_t)(tv * 16 + c) * SEQ + K * 128 + ks * 32 + q * 8);
#pragma unroll
      for (int tv = 0; tv < 4; ++tv)
        oacc[tv] = __builtin_amdgcn_mfma_f32_16x16x32_f16(af, bv[tv], oacc[tv], 0, 0, 0);
    }
  }

  // ---- write unnormalized partial: pO[(h,I,s)][128][64] f16, pML[(h,I,s)][2][128] f32 ----
  int slot = (head * 16 + I) * MAXSPLIT + s;
  f16* po = pO + (size_t)slot * (128 * 64);
  float* pml = pML + (size_t)slot * 256;
  if (c == 0) {
#pragma unroll
    for (int r = 0; r < 4; ++r) {
      int row = rw + q * 4 + r;
      pml[row] = m_i[r];
      pml[128 + row] = l_i[r];
    }
  }
#pragma unroll
  for (int tv = 0; tv < 4; ++tv)
#pragma unroll
    for (int r = 0; r < 4; ++r) {
      int row = rw + q * 4 + r;
      int col = tv * 16 + c;
      po[row * 64 + col] = (f16)oacc[tv][r];
    }
}

// ---------------- merge partials -> oh [2048][1024] f16 ----------------
__global__ __launch_bounds__(256) void k_merge(const f16* __restrict__ pO, const float* __restrict__ pML,
                                               f16* __restrict__ oh) {
  int head = blockIdx.x >> 4, I = blockIdx.x & 15;
  int S_ = nsplits(I);
  int tid = threadIdx.x;
  int row = tid >> 1, half = tid & 1;
  int base = (head * 16 + I) * MAXSPLIT;
  float m[MAXSPLIT], lv[MAXSPLIT];
  float mstar = -INFINITY;
#pragma unroll
  for (int s = 0; s < MAXSPLIT; ++s)
    if (s < S_) {
      m[s] = pML[(size_t)(base + s) * 256 + row];
      lv[s] = pML[(size_t)(base + s) * 256 + 128 + row];
      mstar = fmaxf(mstar, m[s]);
    }
  float wt[MAXSPLIT];
  float lsum = 0.f;
#pragma unroll
  for (int s = 0; s < MAXSPLIT; ++s)
    if (s < S_) {
      wt[s] = __expf(m[s] - mstar);
      lsum += lv[s] * wt[s];
    }
  float rinv = __builtin_amdgcn_rcpf(lsum);
#pragma unroll
  for (int cc = 0; cc < 32; cc += 8) {
    float acc[8] = {0.f, 0.f, 0.f, 0.f, 0.f, 0.f, 0.f, 0.f};
#pragma unroll
    for (int s = 0; s < MAXSPLIT; ++s)
      if (s < S_) {
        f16x8 v = *(const f16x8*)(pO + (size_t)(base + s) * 8192 + row * 64 + half * 32 + cc);
#pragma unroll
        for (int e = 0; e < 8; ++e) acc[e] += wt[s] * (float)v[e];
      }
    f16x8 o;
#pragma unroll
    for (int e = 0; e < 8; ++e) o[e] = (f16)(acc[e] * rinv);
    *(f16x8*)(oh + (size_t)(I * 128 + row) * DIM + head * 64 + half * 32 + cc) = o;
  }
}

// ---------------- final GEMM: oh[2048,1024] @ WoT[1024,1024]^T -> fp32 out ----------------
__global__ __launch_bounds__(256) void k_gemm_out(const f16* __restrict__ A, const f16* __restrict__ B,
                                                  float* __restrict__ out) {
  __shared__ f16 sa[128 * 72];
  __shared__ f16 sb[128 * 72];
  int bx = blockIdx.x, by = blockIdx.y;
  int tid = threadIdx.x, w = tid >> 6, l = tid & 63, q = l >> 4, c = l & 15;
  f32x4 acc[2][8];
  const f32x4 zf = {0.f, 0.f, 0.f, 0.f};
  for (int i = 0; i < 2; ++i) for (int j = 0; j < 8; ++j) acc[i][j] = zf;
  for (int kt = 0; kt < DIM / 64; ++kt) {
    __syncthreads();
#pragma unroll
    for (int it = 0; it < 4; ++it) {
      int idx = it * 256 + tid; int r = idx >> 3, ch = idx & 7;
      *(float4*)(sa + r * 72 + ch * 8) = *(const float4*)(A + (size_t)(by * 128 + r) * DIM + kt * 64 + ch * 8);
      *(float4*)(sb + r * 72 + ch * 8) = *(const float4*)(B + (size_t)(bx * 128 + r) * DIM + kt * 64 + ch * 8);
    }
    __syncthreads();
#pragma unroll
    for (int ks = 0; ks < 2; ++ks) {
      f16x8 af[2], bf[8];
#pragma unroll
      for (int tr = 0; tr < 2; ++tr) af[tr] = *(const f16x8*)(sa + (w * 32 + tr * 16 + c) * 72 + ks * 32 + q * 8);
#pragma unroll
      for (int tc = 0; tc < 8; ++tc) bf[tc] = *(const f16x8*)(sb + (tc * 16 + c) * 72 + ks * 32 + q * 8);
#pragma unroll
      for (int tr = 0; tr < 2; ++tr)
#pragma unroll
        for (int tc = 0; tc < 8; ++tc)
          acc[tr][tc] = __builtin_amdgcn_mfma_f32_16x16x32_f16(af[tr], bf[tc], acc[tr][tc], 0, 0, 0);
    }
  }
#pragma unroll
  for (int tr = 0; tr < 2; ++tr)
#pragma unroll
    for (int tc = 0; tc < 8; ++tc)
#pragma unroll
      for (int r = 0; r < 4; ++r) {
        int row = by * 128 + w * 32 + tr * 16 + q * 4 + r;
        int col = bx * 128 + tc * 16 + c;
        out[(size_t)row * DIM + col] = acc[tr][tc][r];
      }
}

extern "C" void kernel_launch(void* const* d_in, const int* in_sizes, int n_in,
                              void* d_out, int out_size, void* d_ws, size_t ws_size,
                              hipStream_t stream) {
  const float* x  = (const float*)d_in[0];
  const float* Wq = (const float*)d_in[1];
  const float* Wo = (const float*)d_in[2];
  float* out = (float*)d_out;

  f16* ws = (f16*)d_ws;
  size_t off = 0;
  f16* q6  = ws + off; off += (size_t)6 * NHSD;                       // 25.2 MB
  f16* xh  = ws + off; off += (size_t)SEQ * DIM;                      // 4 MB
  f16* WqT = ws + off; off += (size_t)NCOLS * DIM;                    // 12.6 MB
  f16* WoT = ws + off; off += (size_t)DIM * DIM;                      // 2 MB
  f16* oh  = ws + off; off += (size_t)SEQ * DIM;                      // 4 MB
  f16* pO  = ws + off; off += (size_t)NH * 16 * MAXSPLIT * 128 * 64;  // 16.8 MB
  float* pML = (float*)(ws + off); off += (size_t)NH * 16 * MAXSPLIT * 256 * 2; // 1 MB
  // total ~66 MB of workspace

  k_cast_x<<<(SEQ * DIM) / 1024, 256, 0, stream>>>(x, xh);
  k_tcast<<<dim3(NCOLS / 64, DIM / 64), 256, 0, stream>>>(Wq, WqT, DIM, NCOLS);
  k_tcast<<<dim3(DIM / 64, DIM / 64), 256, 0, stream>>>(Wo, WoT, DIM, DIM);
  k_gemm_qkv<<<dim3(NCOLS / 128, SEQ / 128), 256, 0, stream>>>(xh, WqT, q6);
  k_flash<<<NH * SPLITS_PER_HEAD, 512, 0, stream>>>(q6, pO, pML);
  k_merge<<<NH * 16, 256, 0, stream>>>(pO, pML, oh);
  k_gemm_out<<<dim3(DIM / 128, SEQ / 128), 256, 0, stream>>>(oh, WoT, out);
}

// Round 7
// 874.237 us; speedup vs baseline: 1.7869x; 1.7869x over previous
//
#include <hip/hip_runtime.h>
#include <math.h>

typedef _Float16 f16;
typedef _Float16 f16x4 __attribute__((ext_vector_type(4)));
typedef _Float16 f16x8 __attribute__((ext_vector_type(8)));
typedef float f32x4 __attribute__((ext_vector_type(4)));

#define SEQ   2048
#define DIM   1024
#define NH    16
#define DH    64
#define NCOLS 6144
#define NHSD  (NH*SEQ*DH)   /* 2,097,152 elements per qkv sub-tensor */
#define MAXSPLIT 4
#define SPLITS_PER_HEAD 32  /* sum of S(I) over I=0..15 */

__device__ __forceinline__ int nsplits(int I) {
  return (I < 7) ? 1 : (I < 11) ? 2 : (I < 14) ? 3 : 4;
}

// ---------------- cast x (fp32 -> f16), vectorized x4 ----------------
__global__ __launch_bounds__(256) void k_cast_x(const float* __restrict__ x, f16* __restrict__ xh) {
  int i = (blockIdx.x * 256 + threadIdx.x) * 4;
  float4 v = *(const float4*)(x + i);
  f16x4 h; h[0] = (f16)v.x; h[1] = (f16)v.y; h[2] = (f16)v.z; h[3] = (f16)v.w;
  *(f16x4*)(xh + i) = h;
}

// ------------- transpose + cast: out[c][r] = (f16) in[r][c], in is R x C -------------
__global__ __launch_bounds__(256) void k_tcast(const float* __restrict__ in, f16* __restrict__ out,
                                               int R, int C) {
  __shared__ f16 t[64 * 66];
  int bc = blockIdx.x, br = blockIdx.y;
  for (int it = 0; it < 16; ++it) {
    int idx = it * 256 + threadIdx.x;
    int r = idx >> 6, c = idx & 63;
    t[r * 66 + c] = (f16)in[(size_t)(br * 64 + r) * C + bc * 64 + c];
  }
  __syncthreads();
  for (int it = 0; it < 16; ++it) {
    int idx = it * 256 + threadIdx.x;
    int oc = idx >> 6, orr = idx & 63;
    out[(size_t)(bc * 64 + oc) * R + br * 64 + orr] = t[orr * 66 + oc];
  }
}

// ---------------- qkv GEMM: xh[2048,1024] @ WqT[6144,1024]^T -> six packed tensors ----------------
__global__ __launch_bounds__(256) void k_gemm_qkv(const f16* __restrict__ A, const f16* __restrict__ B,
                                                  f16* __restrict__ q6) {
  __shared__ f16 sa[128 * 72];
  __shared__ f16 sb[128 * 72];
  int bx = blockIdx.x, by = blockIdx.y;
  int tid = threadIdx.x, w = tid >> 6, l = tid & 63, q = l >> 4, c = l & 15;
  f32x4 acc[2][8];
  const f32x4 zf = {0.f, 0.f, 0.f, 0.f};
  for (int i = 0; i < 2; ++i) for (int j = 0; j < 8; ++j) acc[i][j] = zf;

  for (int kt = 0; kt < DIM / 64; ++kt) {
    __syncthreads();
#pragma unroll
    for (int it = 0; it < 4; ++it) {
      int idx = it * 256 + tid; int r = idx >> 3, ch = idx & 7;
      *(float4*)(sa + r * 72 + ch * 8) = *(const float4*)(A + (size_t)(by * 128 + r) * DIM + kt * 64 + ch * 8);
      *(float4*)(sb + r * 72 + ch * 8) = *(const float4*)(B + (size_t)(bx * 128 + r) * DIM + kt * 64 + ch * 8);
    }
    __syncthreads();
#pragma unroll
    for (int ks = 0; ks < 2; ++ks) {
      f16x8 af[2], bf[8];
#pragma unroll
      for (int tr = 0; tr < 2; ++tr) af[tr] = *(const f16x8*)(sa + (w * 32 + tr * 16 + c) * 72 + ks * 32 + q * 8);
#pragma unroll
      for (int tc = 0; tc < 8; ++tc) bf[tc] = *(const f16x8*)(sb + (tc * 16 + c) * 72 + ks * 32 + q * 8);
#pragma unroll
      for (int tr = 0; tr < 2; ++tr)
#pragma unroll
        for (int tc = 0; tc < 8; ++tc)
          acc[tr][tc] = __builtin_amdgcn_mfma_f32_16x16x32_f16(af[tr], bf[tc], acc[tr][tc], 0, 0, 0);
    }
  }
  // epilogue: scatter into qu(0) ku(1) vu(2) qc(3) kc(4) vcT(5); scale qu,qc by dh^-0.5
#pragma unroll
  for (int tr = 0; tr < 2; ++tr)
#pragma unroll
    for (int tc = 0; tc < 8; ++tc)
#pragma unroll
      for (int r = 0; r < 4; ++r) {
        int row = by * 128 + w * 32 + tr * 16 + q * 4 + r;
        int col = bx * 128 + tc * 16 + c;
        float v = acc[tr][tc][r];
        int t = col >> 10, head = (col >> 6) & 15, dh = col & 63;
        if (t == 0 || t == 3) v *= 0.125f;
        if (t == 5) q6[(size_t)5 * NHSD + (size_t)(head * DH + dh) * SEQ + row] = (f16)v;
        else        q6[(size_t)t * NHSD + (size_t)(head * SEQ + row) * DH + dh] = (f16)v;
      }
}

// ---------------- split-K fused flash (R7: 512 threads, 8 waves x 16 rows, VGPR<=128) ----------------
// grid 512 = (head, I, split), XCD-swizzled (2 heads/XCD, R5 win).
// EMPIRICAL launch_bounds model on this compiler: VGPR cap ~= 256/arg2 (data: (256,1)->256,
// (256,2)->128, (512,4)->64). So (512,2) -> cap 128 = exactly the 2-blocks/CU budget
// (2 blocks x 8 waves = 4 waves/SIMD). tacc chunked to 4 accumulators (process each 64-col half of
// a tile to completion) to keep peak live ~110 < 128 -> no spill (R6 at 64 VGPR spilled 2.3 GB).
__global__ __launch_bounds__(512, 2) void k_flash(const f16* __restrict__ q6,
                                                  f16* __restrict__ pO, float* __restrict__ pML) {
  __shared__ f16 sa[128 * 128];
  __shared__ f16 sb[128 * 128];
  int bid = blockIdx.x;
  int head = ((bid & 7) << 1) | ((bid >> 3) & 1);
  int rsub = bid >> 4;          // [0,32): split-block index within head
  // decode (I, s) from rsub
  int I = 0, s = 0;
  {
    int acc = 0;
    for (int ii = 0; ii < 16; ++ii) {
      int si = nsplits(ii);
      if (rsub >= acc && rsub < acc + si) { I = ii; s = rsub - acc; }
      acc += si;
    }
  }
  int S_ = nsplits(I);
  int C = (I + 1) * (I + 2) / 2;
  // midpoint equal-cost partition of K in [0,I]
  int K0 = 16, K1 = 0;
  {
    int p = 0;
    for (int K = 0; K <= I; ++K) {
      int cost = I - K + 1;
      int seg = ((2 * p + cost) * S_) / (2 * C);
      if (seg == s) { if (K < K0) K0 = K; K1 = K + 1; }
      p += cost;
    }
  }

  const f16* qu = q6 + (size_t)0 * NHSD + (size_t)head * SEQ * DH;   // pre-scaled by dh^-0.5
  const f16* ku = q6 + (size_t)1 * NHSD + (size_t)head * SEQ * DH;
  const f16* vu = q6 + (size_t)2 * NHSD + (size_t)head * SEQ * DH;
  const f16* qc = q6 + (size_t)3 * NHSD + (size_t)head * SEQ * DH;   // pre-scaled by dh^-0.5
  const f16* kc = q6 + (size_t)4 * NHSD + (size_t)head * SEQ * DH;
  const f16* vt = q6 + (size_t)5 * NHSD + (size_t)head * DH * SEQ;   // vc transposed [64][2048]
  int tid = threadIdx.x, w = tid >> 6, l = tid & 63, q = l >> 4, c = l & 15;
  int rw = w * 16;   // this wave's row base within the 128-row tile

  f32x4 su[8], oacc[4];
  float m_i[4], l_i[4];
  const f32x4 zf = {0.f, 0.f, 0.f, 0.f};
  for (int tv = 0; tv < 4; ++tv) oacc[tv] = zf;
  for (int r = 0; r < 4; ++r) { m_i[r] = -INFINITY; l_i[r] = 0.f; }

  for (int K = K0; K < K1; ++K) {
#pragma unroll
    for (int tc = 0; tc < 8; ++tc) su[tc] = zf;

    for (int J = K; J <= I; ++J) {
      __syncthreads();   // WAR: prior Su-MFMA reads of sb complete before restaging

      // ---- lookahead(K,J): sigmoid(qu_s(K) @ ku(J)^T), keep j>k -> sb; 64 cols at a time ----
#pragma unroll
      for (int th = 0; th < 2; ++th) {
        f32x4 tacc[4];
#pragma unroll
        for (int t4 = 0; t4 < 4; ++t4) tacc[t4] = zf;
#pragma unroll
        for (int ks = 0; ks < 2; ++ks) {
          f16x8 aq = *(const f16x8*)(qu + (size_t)(K * 128 + rw + c) * DH + ks * 32 + q * 8);
          f16x8 bf[4];
#pragma unroll
          for (int t4 = 0; t4 < 4; ++t4)
            bf[t4] = *(const f16x8*)(ku + (size_t)(J * 128 + (th * 4 + t4) * 16 + c) * DH + ks * 32 + q * 8);
#pragma unroll
          for (int t4 = 0; t4 < 4; ++t4)
            tacc[t4] = __builtin_amdgcn_mfma_f32_16x16x32_f16(aq, bf[t4], tacc[t4], 0, 0, 0);
        }
#pragma unroll
        for (int t4 = 0; t4 < 4; ++t4)
#pragma unroll
          for (int r = 0; r < 4; ++r) {
            int row = rw + q * 4 + r;
            int col = (th * 4 + t4) * 16 + c;
            int kg = K * 128 + row, jg = J * 128 + col;
            float v = tacc[t4][r];
            f16 ov = (jg > kg) ? (f16)__builtin_amdgcn_rcpf(1.f + __expf(-v)) : (f16)(0.f);
            sb[(row << 7) + (((col >> 3) ^ (row & 15)) << 3) + (col & 7)] = ov;
          }
      }

      // ---- term1(I,J): qc_s(I) @ vu(J)^T, keep j<=i -> sa; 64 cols at a time ----
#pragma unroll
      for (int th = 0; th < 2; ++th) {
        f32x4 tacc[4];
#pragma unroll
        for (int t4 = 0; t4 < 4; ++t4) tacc[t4] = zf;
#pragma unroll
        for (int ks = 0; ks < 2; ++ks) {
          f16x8 aq = *(const f16x8*)(qc + (size_t)(I * 128 + rw + c) * DH + ks * 32 + q * 8);
          f16x8 bf[4];
#pragma unroll
          for (int t4 = 0; t4 < 4; ++t4)
            bf[t4] = *(const f16x8*)(vu + (size_t)(J * 128 + (th * 4 + t4) * 16 + c) * DH + ks * 32 + q * 8);
#pragma unroll
          for (int t4 = 0; t4 < 4; ++t4)
            tacc[t4] = __builtin_amdgcn_mfma_f32_16x16x32_f16(aq, bf[t4], tacc[t4], 0, 0, 0);
        }
#pragma unroll
        for (int t4 = 0; t4 < 4; ++t4)
#pragma unroll
          for (int r = 0; r < 4; ++r) {
            int row = rw + q * 4 + r;
            int col = (th * 4 + t4) * 16 + c;
            int ig = I * 128 + row, jg = J * 128 + col;
            float v = tacc[t4][r];
            f16 ov = (jg <= ig) ? (f16)v : (f16)(0.f);
            sa[(row << 7) + (((col >> 3) ^ (row & 15)) << 3) + (col & 7)] = ov;
          }
      }

      __syncthreads();   // RAW: sb (lk tile) visible to all waves

      // ---- Su += t1 @ lk^T over j (128 = 4 chunks of 32) ----
#pragma unroll
      for (int ks = 0; ks < 4; ++ks) {
        int ck = ks * 4 + q;
        f16x8 af = *(const f16x8*)(sa + ((rw + c) << 7) + ((ck ^ c) << 3));
        f16x8 bf[4];
#pragma unroll
        for (int th = 0; th < 2; ++th) {
#pragma unroll
          for (int t4 = 0; t4 < 4; ++t4)
            bf[t4] = *(const f16x8*)(sb + (((th * 4 + t4) * 16 + c) << 7) + ((ck ^ c) << 3));
#pragma unroll
          for (int t4 = 0; t4 < 4; ++t4)
            su[th * 4 + t4] = __builtin_amdgcn_mfma_f32_16x16x32_f16(af, bf[t4], su[th * 4 + t4], 0, 0, 0);
        }
      }
    }

    // scores = Sc - silu(Su): su = -silu(su), then MFMA adds Sc on top
#pragma unroll
    for (int tc = 0; tc < 8; ++tc)
#pragma unroll
      for (int r = 0; r < 4; ++r) {
        float v = su[tc][r];
        su[tc][r] = -v * __builtin_amdgcn_rcpf(1.f + __expf(-v));
      }
#pragma unroll
    for (int ks = 0; ks < 2; ++ks) {
      f16x8 aq = *(const f16x8*)(qc + (size_t)(I * 128 + rw + c) * DH + ks * 32 + q * 8);
#pragma unroll
      for (int th = 0; th < 2; ++th) {
        f16x8 bk[4];
#pragma unroll
        for (int t4 = 0; t4 < 4; ++t4)
          bk[t4] = *(const f16x8*)(kc + (size_t)(K * 128 + (th * 4 + t4) * 16 + c) * DH + ks * 32 + q * 8);
#pragma unroll
        for (int t4 = 0; t4 < 4; ++t4)
          su[th * 4 + t4] = __builtin_amdgcn_mfma_f32_16x16x32_f16(aq, bk[t4], su[th * 4 + t4], 0, 0, 0);
      }
    }
    if (K == I) {   // strict causal mask inside the diagonal block
#pragma unroll
      for (int tc = 0; tc < 8; ++tc)
#pragma unroll
        for (int r = 0; r < 4; ++r) {
          int rg = rw + q * 4 + r;
          int cg = tc * 16 + c;
          if (cg > rg) su[tc][r] = -INFINITY;
        }
    }
    // online softmax (row owned by 16 lanes sharing q; reduce across low-4 lane bits)
#pragma unroll
    for (int r = 0; r < 4; ++r) {
      float mx = su[0][r];
#pragma unroll
      for (int tc = 1; tc < 8; ++tc) mx = fmaxf(mx, su[tc][r]);
      mx = fmaxf(mx, __shfl_xor(mx, 1)); mx = fmaxf(mx, __shfl_xor(mx, 2));
      mx = fmaxf(mx, __shfl_xor(mx, 4)); mx = fmaxf(mx, __shfl_xor(mx, 8));
      float mnew  = fmaxf(m_i[r], mx);
      float alpha = __expf(m_i[r] - mnew);
      float ssum = 0.f;
#pragma unroll
      for (int tc = 0; tc < 8; ++tc) {
        float pp = __expf(su[tc][r] - mnew);
        su[tc][r] = pp;
        ssum += pp;
      }
      ssum += __shfl_xor(ssum, 1); ssum += __shfl_xor(ssum, 2);
      ssum += __shfl_xor(ssum, 4); ssum += __shfl_xor(ssum, 8);
      l_i[r] = l_i[r] * alpha + ssum;
      m_i[r] = mnew;
#pragma unroll
      for (int tv = 0; tv < 4; ++tv) oacc[tv][r] *= alpha;
    }
    // write P into sa (own 16 rows only -> no barrier; other waves never touch these rows)
#pragma unroll
    for (int tc = 0; tc < 8; ++tc)
#pragma unroll
      for (int r = 0; r < 4; ++r) {
        int row = rw + q * 4 + r;
        int col = tc * 16 + c;
        sa[(row << 7) + (((col >> 3) ^ (row & 15)) << 3) + (col & 7)] = (f16)su[tc][r];
      }
    // PV: A = P (own LDS rows), B = vcT straight from global (L2-resident)
#pragma unroll
    for (int ks = 0; ks < 4; ++ks) {
      int ck = ks * 4 + q;
      f16x8 af = *(const f16x8*)(sa + ((rw + c) << 7) + ((ck ^ c) << 3));
      f16x8 bv[4];
#pragma unroll
      for (int tv = 0; tv < 4; ++tv)
        bv[tv] = *(const f16x8*)(vt + (size_t)(tv * 16 + c) * SEQ + K * 128 + ks * 32 + q * 8);
#pragma unroll
      for (int tv = 0; tv < 4; ++tv)
        oacc[tv] = __builtin_amdgcn_mfma_f32_16x16x32_f16(af, bv[tv], oacc[tv], 0, 0, 0);
    }
  }

  // ---- write unnormalized partial: pO[(h,I,s)][128][64] f16, pML[(h,I,s)][2][128] f32 ----
  int slot = (head * 16 + I) * MAXSPLIT + s;
  f16* po = pO + (size_t)slot * (128 * 64);
  float* pml = pML + (size_t)slot * 256;
  if (c == 0) {
#pragma unroll
    for (int r = 0; r < 4; ++r) {
      int row = rw + q * 4 + r;
      pml[row] = m_i[r];
      pml[128 + row] = l_i[r];
    }
  }
#pragma unroll
  for (int tv = 0; tv < 4; ++tv)
#pragma unroll
    for (int r = 0; r < 4; ++r) {
      int row = rw + q * 4 + r;
      int col = tv * 16 + c;
      po[row * 64 + col] = (f16)oacc[tv][r];
    }
}

// ---------------- merge partials -> oh [2048][1024] f16 ----------------
__global__ __launch_bounds__(256) void k_merge(const f16* __restrict__ pO, const float* __restrict__ pML,
                                               f16* __restrict__ oh) {
  int head = blockIdx.x >> 4, I = blockIdx.x & 15;
  int S_ = nsplits(I);
  int tid = threadIdx.x;
  int row = tid >> 1, half = tid & 1;
  int base = (head * 16 + I) * MAXSPLIT;
  float m[MAXSPLIT], lv[MAXSPLIT];
  float mstar = -INFINITY;
#pragma unroll
  for (int s = 0; s < MAXSPLIT; ++s)
    if (s < S_) {
      m[s] = pML[(size_t)(base + s) * 256 + row];
      lv[s] = pML[(size_t)(base + s) * 256 + 128 + row];
      mstar = fmaxf(mstar, m[s]);
    }
  float wt[MAXSPLIT];
  float lsum = 0.f;
#pragma unroll
  for (int s = 0; s < MAXSPLIT; ++s)
    if (s < S_) {
      wt[s] = __expf(m[s] - mstar);
      lsum += lv[s] * wt[s];
    }
  float rinv = __builtin_amdgcn_rcpf(lsum);
#pragma unroll
  for (int cc = 0; cc < 32; cc += 8) {
    float acc[8] = {0.f, 0.f, 0.f, 0.f, 0.f, 0.f, 0.f, 0.f};
#pragma unroll
    for (int s = 0; s < MAXSPLIT; ++s)
      if (s < S_) {
        f16x8 v = *(const f16x8*)(pO + (size_t)(base + s) * 8192 + row * 64 + half * 32 + cc);
#pragma unroll
        for (int e = 0; e < 8; ++e) acc[e] += wt[s] * (float)v[e];
      }
    f16x8 o;
#pragma unroll
    for (int e = 0; e < 8; ++e) o[e] = (f16)(acc[e] * rinv);
    *(f16x8*)(oh + (size_t)(I * 128 + row) * DIM + head * 64 + half * 32 + cc) = o;
  }
}

// ---------------- final GEMM: oh[2048,1024] @ WoT[1024,1024]^T -> fp32 out ----------------
__global__ __launch_bounds__(256) void k_gemm_out(const f16* __restrict__ A, const f16* __restrict__ B,
                                                  float* __restrict__ out) {
  __shared__ f16 sa[128 * 72];
  __shared__ f16 sb[128 * 72];
  int bx = blockIdx.x, by = blockIdx.y;
  int tid = threadIdx.x, w = tid >> 6, l = tid & 63, q = l >> 4, c = l & 15;
  f32x4 acc[2][8];
  const f32x4 zf = {0.f, 0.f, 0.f, 0.f};
  for (int i = 0; i < 2; ++i) for (int j = 0; j < 8; ++j) acc[i][j] = zf;
  for (int kt = 0; kt < DIM / 64; ++kt) {
    __syncthreads();
#pragma unroll
    for (int it = 0; it < 4; ++it) {
      int idx = it * 256 + tid; int r = idx >> 3, ch = idx & 7;
      *(float4*)(sa + r * 72 + ch * 8) = *(const float4*)(A + (size_t)(by * 128 + r) * DIM + kt * 64 + ch * 8);
      *(float4*)(sb + r * 72 + ch * 8) = *(const float4*)(B + (size_t)(bx * 128 + r) * DIM + kt * 64 + ch * 8);
    }
    __syncthreads();
#pragma unroll
    for (int ks = 0; ks < 2; ++ks) {
      f16x8 af[2], bf[8];
#pragma unroll
      for (int tr = 0; tr < 2; ++tr) af[tr] = *(const f16x8*)(sa + (w * 32 + tr * 16 + c) * 72 + ks * 32 + q * 8);
#pragma unroll
      for (int tc = 0; tc < 8; ++tc) bf[tc] = *(const f16x8*)(sb + (tc * 16 + c) * 72 + ks * 32 + q * 8);
#pragma unroll
      for (int tr = 0; tr < 2; ++tr)
#pragma unroll
        for (int tc = 0; tc < 8; ++tc)
          acc[tr][tc] = __builtin_amdgcn_mfma_f32_16x16x32_f16(af[tr], bf[tc], acc[tr][tc], 0, 0, 0);
    }
  }
#pragma unroll
  for (int tr = 0; tr < 2; ++tr)
#pragma unroll
    for (int tc = 0; tc < 8; ++tc)
#pragma unroll
      for (int r = 0; r < 4; ++r) {
        int row = by * 128 + w * 32 + tr * 16 + q * 4 + r;
        int col = bx * 128 + tc * 16 + c;
        out[(size_t)row * DIM + col] = acc[tr][tc][r];
      }
}

extern "C" void kernel_launch(void* const* d_in, const int* in_sizes, int n_in,
                              void* d_out, int out_size, void* d_ws, size_t ws_size,
                              hipStream_t stream) {
  const float* x  = (const float*)d_in[0];
  const float* Wq = (const float*)d_in[1];
  const float* Wo = (const float*)d_in[2];
  float* out = (float*)d_out;

  f16* ws = (f16*)d_ws;
  size_t off = 0;
  f16* q6  = ws + off; off += (size_t)6 * NHSD;                       // 25.2 MB
  f16* xh  = ws + off; off += (size_t)SEQ * DIM;                      // 4 MB
  f16* WqT = ws + off; off += (size_t)NCOLS * DIM;                    // 12.6 MB
  f16* WoT = ws + off; off += (size_t)DIM * DIM;                      // 2 MB
  f16* oh  = ws + off; off += (size_t)SEQ * DIM;                      // 4 MB
  f16* pO  = ws + off; off += (size_t)NH * 16 * MAXSPLIT * 128 * 64;  // 16.8 MB
  float* pML = (float*)(ws + off); off += (size_t)NH * 16 * MAXSPLIT * 256 * 2; // 1 MB
  // total ~66 MB of workspace

  k_cast_x<<<(SEQ * DIM) / 1024, 256, 0, stream>>>(x, xh);
  k_tcast<<<dim3(NCOLS / 64, DIM / 64), 256, 0, stream>>>(Wq, WqT, DIM, NCOLS);
  k_tcast<<<dim3(DIM / 64, DIM / 64), 256, 0, stream>>>(Wo, WoT, DIM, DIM);
  k_gemm_qkv<<<dim3(NCOLS / 128, SEQ / 128), 256, 0, stream>>>(xh, WqT, q6);
  k_flash<<<NH * SPLITS_PER_HEAD, 512, 0, stream>>>(q6, pO, pML);
  k_merge<<<NH * 16, 256, 0, stream>>>(pO, pML, oh);
  k_gemm_out<<<dim3(DIM / 128, SEQ / 128), 256, 0, stream>>>(oh, WoT, out);
}

// Round 8
// 738.626 us; speedup vs baseline: 2.1149x; 1.1836x over previous
//
#include <hip/hip_runtime.h>
#include <math.h>

typedef _Float16 f16;
typedef _Float16 f16x4 __attribute__((ext_vector_type(4)));
typedef _Float16 f16x8 __attribute__((ext_vector_type(8)));
typedef float f32x4 __attribute__((ext_vector_type(4)));

#define SEQ   2048
#define DIM   1024
#define NH    16
#define DH    64
#define NCOLS 6144
#define NHSD  (NH*SEQ*DH)   /* 2,097,152 elements per qkv sub-tensor */
#define MAXSPLIT 6
#define SPLITS_PER_HEAD 40  /* sum of NS[] over I=0..15 */

// R8: finer splits — target <=24 (K,J) steps per block (costs: I<6 single 1..21; then 14,18,23,18,
// 22,26,23,26,24,23). Grid 640 > 512 CU-slots -> last 128 blocks fill freed slots dynamically.
__device__ __forceinline__ int nsplits(int I) {
  const int NS[16] = {1,1,1,1,1,1,2,2,2,3,3,3,4,4,5,6};
  return NS[I];
}

// ---------------- cast x (fp32 -> f16), vectorized x4 ----------------
__global__ __launch_bounds__(256) void k_cast_x(const float* __restrict__ x, f16* __restrict__ xh) {
  int i = (blockIdx.x * 256 + threadIdx.x) * 4;
  float4 v = *(const float4*)(x + i);
  f16x4 h; h[0] = (f16)v.x; h[1] = (f16)v.y; h[2] = (f16)v.z; h[3] = (f16)v.w;
  *(f16x4*)(xh + i) = h;
}

// ------------- transpose + cast: out[c][r] = (f16) in[r][c], in is R x C -------------
__global__ __launch_bounds__(256) void k_tcast(const float* __restrict__ in, f16* __restrict__ out,
                                               int R, int C) {
  __shared__ f16 t[64 * 66];
  int bc = blockIdx.x, br = blockIdx.y;
  for (int it = 0; it < 16; ++it) {
    int idx = it * 256 + threadIdx.x;
    int r = idx >> 6, c = idx & 63;
    t[r * 66 + c] = (f16)in[(size_t)(br * 64 + r) * C + bc * 64 + c];
  }
  __syncthreads();
  for (int it = 0; it < 16; ++it) {
    int idx = it * 256 + threadIdx.x;
    int oc = idx >> 6, orr = idx & 63;
    out[(size_t)(bc * 64 + oc) * R + br * 64 + orr] = t[orr * 66 + oc];
  }
}

// ---------------- qkv GEMM: xh[2048,1024] @ WqT[6144,1024]^T -> six packed tensors ----------------
__global__ __launch_bounds__(256) void k_gemm_qkv(const f16* __restrict__ A, const f16* __restrict__ B,
                                                  f16* __restrict__ q6) {
  __shared__ f16 sa[128 * 72];
  __shared__ f16 sb[128 * 72];
  int bx = blockIdx.x, by = blockIdx.y;
  int tid = threadIdx.x, w = tid >> 6, l = tid & 63, q = l >> 4, c = l & 15;
  f32x4 acc[2][8];
  const f32x4 zf = {0.f, 0.f, 0.f, 0.f};
  for (int i = 0; i < 2; ++i) for (int j = 0; j < 8; ++j) acc[i][j] = zf;

  for (int kt = 0; kt < DIM / 64; ++kt) {
    __syncthreads();
#pragma unroll
    for (int it = 0; it < 4; ++it) {
      int idx = it * 256 + tid; int r = idx >> 3, ch = idx & 7;
      *(float4*)(sa + r * 72 + ch * 8) = *(const float4*)(A + (size_t)(by * 128 + r) * DIM + kt * 64 + ch * 8);
      *(float4*)(sb + r * 72 + ch * 8) = *(const float4*)(B + (size_t)(bx * 128 + r) * DIM + kt * 64 + ch * 8);
    }
    __syncthreads();
#pragma unroll
    for (int ks = 0; ks < 2; ++ks) {
      f16x8 af[2], bf[8];
#pragma unroll
      for (int tr = 0; tr < 2; ++tr) af[tr] = *(const f16x8*)(sa + (w * 32 + tr * 16 + c) * 72 + ks * 32 + q * 8);
#pragma unroll
      for (int tc = 0; tc < 8; ++tc) bf[tc] = *(const f16x8*)(sb + (tc * 16 + c) * 72 + ks * 32 + q * 8);
#pragma unroll
      for (int tr = 0; tr < 2; ++tr)
#pragma unroll
        for (int tc = 0; tc < 8; ++tc)
          acc[tr][tc] = __builtin_amdgcn_mfma_f32_16x16x32_f16(af[tr], bf[tc], acc[tr][tc], 0, 0, 0);
    }
  }
  // epilogue: scatter into qu(0) ku(1) vu(2) qc(3) kc(4) vcT(5); scale qu,qc by dh^-0.5
#pragma unroll
  for (int tr = 0; tr < 2; ++tr)
#pragma unroll
    for (int tc = 0; tc < 8; ++tc)
#pragma unroll
      for (int r = 0; r < 4; ++r) {
        int row = by * 128 + w * 32 + tr * 16 + q * 4 + r;
        int col = bx * 128 + tc * 16 + c;
        float v = acc[tr][tc][r];
        int t = col >> 10, head = (col >> 6) & 15, dh = col & 63;
        if (t == 0 || t == 3) v *= 0.125f;
        if (t == 5) q6[(size_t)5 * NHSD + (size_t)(head * DH + dh) * SEQ + row] = (f16)v;
        else        q6[(size_t)t * NHSD + (size_t)(head * SEQ + row) * DH + dh] = (f16)v;
      }
}

// ---------------- split-K fused flash (R8: R5 structure + finer splits + hoisted A-frags) ----------------
// 256 threads, 4 waves x 32 rows (R5's best: 638us; R7's 8x16 contended and regressed).
// grid 640 = (head XCD-swizzled low 4 bits, rsub=bid>>4 in [0,40)). launch_bounds(256,1): natural
// 256 VGPR, no spill (R3/R6 lesson: forced caps spill GBs). 2 blocks/CU co-resident via HW.
// R8 adds: (a) finer splits, max ~24 steps/block + 128 dynamically-dispatched tail blocks;
// (b) a_qc hoisted kernel-wide, a_qu hoisted per-K (removes 8 L2-latency loads/step).
__global__ __launch_bounds__(256, 1) void k_flash(const f16* __restrict__ q6,
                                                  f16* __restrict__ pO, float* __restrict__ pML) {
  __shared__ f16 sa[128 * 128];
  __shared__ f16 sb[128 * 128];
  int bid = blockIdx.x;
  int head = ((bid & 7) << 1) | ((bid >> 3) & 1);
  int rsub = bid >> 4;          // [0,40): split-block index within head
  // decode (I, s) from rsub
  int I = 0, s = 0;
  {
    int acc = 0;
    for (int ii = 0; ii < 16; ++ii) {
      int si = nsplits(ii);
      if (rsub >= acc && rsub < acc + si) { I = ii; s = rsub - acc; }
      acc += si;
    }
  }
  int S_ = nsplits(I);
  int C = (I + 1) * (I + 2) / 2;
  // midpoint equal-cost partition of K in [0,I]
  int K0 = 16, K1 = 0;
  {
    int p = 0;
    for (int K = 0; K <= I; ++K) {
      int cost = I - K + 1;
      int seg = ((2 * p + cost) * S_) / (2 * C);
      if (seg == s) { if (K < K0) K0 = K; K1 = K + 1; }
      p += cost;
    }
  }

  const f16* qu = q6 + (size_t)0 * NHSD + (size_t)head * SEQ * DH;   // pre-scaled by dh^-0.5
  const f16* ku = q6 + (size_t)1 * NHSD + (size_t)head * SEQ * DH;
  const f16* vu = q6 + (size_t)2 * NHSD + (size_t)head * SEQ * DH;
  const f16* qc = q6 + (size_t)3 * NHSD + (size_t)head * SEQ * DH;   // pre-scaled by dh^-0.5
  const f16* kc = q6 + (size_t)4 * NHSD + (size_t)head * SEQ * DH;
  const f16* vt = q6 + (size_t)5 * NHSD + (size_t)head * DH * SEQ;   // vc transposed [64][2048]
  int tid = threadIdx.x, w = tid >> 6, l = tid & 63, q = l >> 4, c = l & 15;

  // Hoisted A-frags: qc_s(I) rows are used by every t1 tile AND the Sc MFMA.
  f16x8 a_qc[2][2];
#pragma unroll
  for (int tr = 0; tr < 2; ++tr)
#pragma unroll
    for (int ks = 0; ks < 2; ++ks)
      a_qc[tr][ks] = *(const f16x8*)(qc + (size_t)(I * 128 + w * 32 + tr * 16 + c) * DH + ks * 32 + q * 8);

  f32x4 su[2][8], tacc[2][8], oacc[2][4];
  float m_i[2][4], l_i[2][4];
  const f32x4 zf = {0.f, 0.f, 0.f, 0.f};
  for (int tr = 0; tr < 2; ++tr) for (int tv = 0; tv < 4; ++tv) oacc[tr][tv] = zf;
  for (int tr = 0; tr < 2; ++tr) for (int r = 0; r < 4; ++r) { m_i[tr][r] = -INFINITY; l_i[tr][r] = 0.f; }

  for (int K = K0; K < K1; ++K) {
    // qu_s(K) A-frags: invariant across the J-loop — hoist per K.
    f16x8 a_qu[2][2];
#pragma unroll
    for (int tr = 0; tr < 2; ++tr)
#pragma unroll
      for (int ks = 0; ks < 2; ++ks)
        a_qu[tr][ks] = *(const f16x8*)(qu + (size_t)(K * 128 + w * 32 + tr * 16 + c) * DH + ks * 32 + q * 8);

#pragma unroll
    for (int tr = 0; tr < 2; ++tr) for (int tc = 0; tc < 8; ++tc) su[tr][tc] = zf;

    for (int J = K; J <= I; ++J) {
      __syncthreads();   // WAR: prior Su-MFMA reads of sb complete before restaging

      // ---- lookahead(K,J) tile: sigmoid(qu_s(K) @ ku(J)^T), keep j>k -> sb (own k-rows) ----
      for (int tr = 0; tr < 2; ++tr) for (int tc = 0; tc < 8; ++tc) tacc[tr][tc] = zf;
#pragma unroll
      for (int ks = 0; ks < 2; ++ks) {
        f16x8 bf[8];
#pragma unroll
        for (int tc = 0; tc < 8; ++tc)
          bf[tc] = *(const f16x8*)(ku + (size_t)(J * 128 + tc * 16 + c) * DH + ks * 32 + q * 8);
#pragma unroll
        for (int tr = 0; tr < 2; ++tr)
#pragma unroll
          for (int tc = 0; tc < 8; ++tc)
            tacc[tr][tc] = __builtin_amdgcn_mfma_f32_16x16x32_f16(a_qu[tr][ks], bf[tc], tacc[tr][tc], 0, 0, 0);
      }
#pragma unroll
      for (int tr = 0; tr < 2; ++tr)
#pragma unroll
        for (int tc = 0; tc < 8; ++tc)
#pragma unroll
          for (int r = 0; r < 4; ++r) {
            int row = w * 32 + tr * 16 + q * 4 + r;
            int col = tc * 16 + c;
            int kg = K * 128 + row, jg = J * 128 + col;
            float v = tacc[tr][tc][r];
            f16 ov = (jg > kg) ? (f16)__builtin_amdgcn_rcpf(1.f + __expf(-v)) : (f16)(0.f);
            sb[(row << 7) + (((col >> 3) ^ (row & 15)) << 3) + (col & 7)] = ov;
          }

      // ---- term1(I,J) tile: qc_s(I) @ vu(J)^T, keep j<=i -> sa (own i-rows) ----
      for (int tr = 0; tr < 2; ++tr) for (int tc = 0; tc < 8; ++tc) tacc[tr][tc] = zf;
#pragma unroll
      for (int ks = 0; ks < 2; ++ks) {
        f16x8 bf[8];
#pragma unroll
        for (int tc = 0; tc < 8; ++tc)
          bf[tc] = *(const f16x8*)(vu + (size_t)(J * 128 + tc * 16 + c) * DH + ks * 32 + q * 8);
#pragma unroll
        for (int tr = 0; tr < 2; ++tr)
#pragma unroll
          for (int tc = 0; tc < 8; ++tc)
            tacc[tr][tc] = __builtin_amdgcn_mfma_f32_16x16x32_f16(a_qc[tr][ks], bf[tc], tacc[tr][tc], 0, 0, 0);
      }
#pragma unroll
      for (int tr = 0; tr < 2; ++tr)
#pragma unroll
        for (int tc = 0; tc < 8; ++tc)
#pragma unroll
          for (int r = 0; r < 4; ++r) {
            int row = w * 32 + tr * 16 + q * 4 + r;
            int col = tc * 16 + c;
            int ig = I * 128 + row, jg = J * 128 + col;
            float v = tacc[tr][tc][r];
            f16 ov = (jg <= ig) ? (f16)v : (f16)(0.f);
            sa[(row << 7) + (((col >> 3) ^ (row & 15)) << 3) + (col & 7)] = ov;
          }

      __syncthreads();   // RAW: sb (lk tile) visible to all waves

      // ---- Su += t1 @ lk^T over j (128 = 4 chunks of 32) ----
#pragma unroll
      for (int ks = 0; ks < 4; ++ks) {
        int ck = ks * 4 + q;
        f16x8 af[2], bf[8];
#pragma unroll
        for (int tr = 0; tr < 2; ++tr)
          af[tr] = *(const f16x8*)(sa + ((w * 32 + tr * 16 + c) << 7) + ((ck ^ c) << 3));
#pragma unroll
        for (int tc = 0; tc < 8; ++tc)
          bf[tc] = *(const f16x8*)(sb + ((tc * 16 + c) << 7) + ((ck ^ c) << 3));
#pragma unroll
        for (int tr = 0; tr < 2; ++tr)
#pragma unroll
          for (int tc = 0; tc < 8; ++tc)
            su[tr][tc] = __builtin_amdgcn_mfma_f32_16x16x32_f16(af[tr], bf[tc], su[tr][tc], 0, 0, 0);
      }
    }

    // scores = Sc - silu(Su): su = -silu(su), then MFMA adds Sc on top
#pragma unroll
    for (int tr = 0; tr < 2; ++tr)
#pragma unroll
      for (int tc = 0; tc < 8; ++tc)
#pragma unroll
        for (int r = 0; r < 4; ++r) {
          float v = su[tr][tc][r];
          su[tr][tc][r] = -v * __builtin_amdgcn_rcpf(1.f + __expf(-v));
        }
#pragma unroll
    for (int ks = 0; ks < 2; ++ks) {
      f16x8 bk[8];
#pragma unroll
      for (int tc = 0; tc < 8; ++tc)
        bk[tc] = *(const f16x8*)(kc + (size_t)(K * 128 + tc * 16 + c) * DH + ks * 32 + q * 8);
#pragma unroll
      for (int tr = 0; tr < 2; ++tr)
#pragma unroll
        for (int tc = 0; tc < 8; ++tc)
          su[tr][tc] = __builtin_amdgcn_mfma_f32_16x16x32_f16(a_qc[tr][ks], bk[tc], su[tr][tc], 0, 0, 0);
    }
    if (K == I) {   // strict causal mask inside the diagonal block
#pragma unroll
      for (int tr = 0; tr < 2; ++tr)
#pragma unroll
        for (int tc = 0; tc < 8; ++tc)
#pragma unroll
          for (int r = 0; r < 4; ++r) {
            int rg = w * 32 + tr * 16 + q * 4 + r;
            int cg = tc * 16 + c;
            if (cg > rg) su[tr][tc][r] = -INFINITY;
          }
    }
    // online softmax (row owned by lanes sharing q; reduce across low-4 lane bits)
#pragma unroll
    for (int tr = 0; tr < 2; ++tr)
#pragma unroll
      for (int r = 0; r < 4; ++r) {
        float mx = su[tr][0][r];
#pragma unroll
        for (int tc = 1; tc < 8; ++tc) mx = fmaxf(mx, su[tr][tc][r]);
        mx = fmaxf(mx, __shfl_xor(mx, 1)); mx = fmaxf(mx, __shfl_xor(mx, 2));
        mx = fmaxf(mx, __shfl_xor(mx, 4)); mx = fmaxf(mx, __shfl_xor(mx, 8));
        float mnew  = fmaxf(m_i[tr][r], mx);
        float alpha = __expf(m_i[tr][r] - mnew);
        float ssum = 0.f;
#pragma unroll
        for (int tc = 0; tc < 8; ++tc) {
          float pp = __expf(su[tr][tc][r] - mnew);
          su[tr][tc][r] = pp;
          ssum += pp;
        }
        ssum += __shfl_xor(ssum, 1); ssum += __shfl_xor(ssum, 2);
        ssum += __shfl_xor(ssum, 4); ssum += __shfl_xor(ssum, 8);
        l_i[tr][r] = l_i[tr][r] * alpha + ssum;
        m_i[tr][r] = mnew;
#pragma unroll
        for (int tv = 0; tv < 4; ++tv) oacc[tr][tv][r] *= alpha;
      }
    // write P into sa (own rows only -> no barrier; other waves never read these rows)
#pragma unroll
    for (int tr = 0; tr < 2; ++tr)
#pragma unroll
      for (int tc = 0; tc < 8; ++tc)
#pragma unroll
        for (int r = 0; r < 4; ++r) {
          int row = w * 32 + tr * 16 + q * 4 + r;
          int col = tc * 16 + c;
          sa[(row << 7) + (((col >> 3) ^ (row & 15)) << 3) + (col & 7)] = (f16)su[tr][tc][r];
        }
    // PV: A = P (own LDS rows), B = vcT straight from global (L2-resident)
#pragma unroll
    for (int ks = 0; ks < 4; ++ks) {
      int ck = ks * 4 + q;
      f16x8 af[2], bv[4];
#pragma unroll
      for (int tr = 0; tr < 2; ++tr)
        af[tr] = *(const f16x8*)(sa + ((w * 32 + tr * 16 + c) << 7) + ((ck ^ c) << 3));
#pragma unroll
      for (int tv = 0; tv < 4; ++tv)
        bv[tv] = *(const f16x8*)(vt + (size_t)(tv * 16 + c) * SEQ + K * 128 + ks * 32 + q * 8);
#pragma unroll
      for (int tr = 0; tr < 2; ++tr)
#pragma unroll
        for (int tv = 0; tv < 4; ++tv)
          oacc[tr][tv] = __builtin_amdgcn_mfma_f32_16x16x32_f16(af[tr], bv[tv], oacc[tr][tv], 0, 0, 0);
    }
  }

  // ---- write unnormalized partial: pO[(h,I,s)][128][64] f16, pML[(h,I,s)][2][128] f32 ----
  int slot = (head * 16 + I) * MAXSPLIT + s;
  f16* po = pO + (size_t)slot * (128 * 64);
  float* pml = pML + (size_t)slot * 256;
  if (c == 0) {
#pragma unroll
    for (int tr = 0; tr < 2; ++tr)
#pragma unroll
      for (int r = 0; r < 4; ++r) {
        int row = w * 32 + tr * 16 + q * 4 + r;
        pml[row] = m_i[tr][r];
        pml[128 + row] = l_i[tr][r];
      }
  }
#pragma unroll
  for (int tr = 0; tr < 2; ++tr)
#pragma unroll
    for (int tv = 0; tv < 4; ++tv)
#pragma unroll
      for (int r = 0; r < 4; ++r) {
        int row = w * 32 + tr * 16 + q * 4 + r;
        int col = tv * 16 + c;
        po[row * 64 + col] = (f16)oacc[tr][tv][r];
      }
}

// ---------------- merge partials -> oh [2048][1024] f16 ----------------
__global__ __launch_bounds__(256) void k_merge(const f16* __restrict__ pO, const float* __restrict__ pML,
                                               f16* __restrict__ oh) {
  int head = blockIdx.x >> 4, I = blockIdx.x & 15;
  int S_ = nsplits(I);
  int tid = threadIdx.x;
  int row = tid >> 1, half = tid & 1;
  int base = (head * 16 + I) * MAXSPLIT;
  float m[MAXSPLIT], lv[MAXSPLIT];
  float mstar = -INFINITY;
#pragma unroll
  for (int s = 0; s < MAXSPLIT; ++s)
    if (s < S_) {
      m[s] = pML[(size_t)(base + s) * 256 + row];
      lv[s] = pML[(size_t)(base + s) * 256 + 128 + row];
      mstar = fmaxf(mstar, m[s]);
    }
  float wt[MAXSPLIT];
  float lsum = 0.f;
#pragma unroll
  for (int s = 0; s < MAXSPLIT; ++s)
    if (s < S_) {
      wt[s] = __expf(m[s] - mstar);
      lsum += lv[s] * wt[s];
    }
  float rinv = __builtin_amdgcn_rcpf(lsum);
#pragma unroll
  for (int cc = 0; cc < 32; cc += 8) {
    float acc[8] = {0.f, 0.f, 0.f, 0.f, 0.f, 0.f, 0.f, 0.f};
#pragma unroll
    for (int s = 0; s < MAXSPLIT; ++s)
      if (s < S_) {
        f16x8 v = *(const f16x8*)(pO + (size_t)(base + s) * 8192 + row * 64 + half * 32 + cc);
#pragma unroll
        for (int e = 0; e < 8; ++e) acc[e] += wt[s] * (float)v[e];
      }
    f16x8 o;
#pragma unroll
    for (int e = 0; e < 8; ++e) o[e] = (f16)(acc[e] * rinv);
    *(f16x8*)(oh + (size_t)(I * 128 + row) * DIM + head * 64 + half * 32 + cc) = o;
  }
}

// ---------------- final GEMM: oh[2048,1024] @ WoT[1024,1024]^T -> fp32 out ----------------
__global__ __launch_bounds__(256) void k_gemm_out(const f16* __restrict__ A, const f16* __restrict__ B,
                                                  float* __restrict__ out) {
  __shared__ f16 sa[128 * 72];
  __shared__ f16 sb[128 * 72];
  int bx = blockIdx.x, by = blockIdx.y;
  int tid = threadIdx.x, w = tid >> 6, l = tid & 63, q = l >> 4, c = l & 15;
  f32x4 acc[2][8];
  const f32x4 zf = {0.f, 0.f, 0.f, 0.f};
  for (int i = 0; i < 2; ++i) for (int j = 0; j < 8; ++j) acc[i][j] = zf;
  for (int kt = 0; kt < DIM / 64; ++kt) {
    __syncthreads();
#pragma unroll
    for (int it = 0; it < 4; ++it) {
      int idx = it * 256 + tid; int r = idx >> 3, ch = idx & 7;
      *(float4*)(sa + r * 72 + ch * 8) = *(const float4*)(A + (size_t)(by * 128 + r) * DIM + kt * 64 + ch * 8);
      *(float4*)(sb + r * 72 + ch * 8) = *(const float4*)(B + (size_t)(bx * 128 + r) * DIM + kt * 64 + ch * 8);
    }
    __syncthreads();
#pragma unroll
    for (int ks = 0; ks < 2; ++ks) {
      f16x8 af[2], bf[8];
#pragma unroll
      for (int tr = 0; tr < 2; ++tr) af[tr] = *(const f16x8*)(sa + (w * 32 + tr * 16 + c) * 72 + ks * 32 + q * 8);
#pragma unroll
      for (int tc = 0; tc < 8; ++tc) bf[tc] = *(const f16x8*)(sb + (tc * 16 + c) * 72 + ks * 32 + q * 8);
#pragma unroll
      for (int tr = 0; tr < 2; ++tr)
#pragma unroll
        for (int tc = 0; tc < 8; ++tc)
          acc[tr][tc] = __builtin_amdgcn_mfma_f32_16x16x32_f16(af[tr], bf[tc], acc[tr][tc], 0, 0, 0);
    }
  }
#pragma unroll
  for (int tr = 0; tr < 2; ++tr)
#pragma unroll
    for (int tc = 0; tc < 8; ++tc)
#pragma unroll
      for (int r = 0; r < 4; ++r) {
        int row = by * 128 + w * 32 + tr * 16 + q * 4 + r;
        int col = bx * 128 + tc * 16 + c;
        out[(size_t)row * DIM + col] = acc[tr][tc][r];
      }
}

extern "C" void kernel_launch(void* const* d_in, const int* in_sizes, int n_in,
                              void* d_out, int out_size, void* d_ws, size_t ws_size,
                              hipStream_t stream) {
  const float* x  = (const float*)d_in[0];
  const float* Wq = (const float*)d_in[1];
  const float* Wo = (const float*)d_in[2];
  float* out = (float*)d_out;

  f16* ws = (f16*)d_ws;
  size_t off = 0;
  f16* q6  = ws + off; off += (size_t)6 * NHSD;                       // 25.2 MB
  f16* xh  = ws + off; off += (size_t)SEQ * DIM;                      // 4 MB
  f16* WqT = ws + off; off += (size_t)NCOLS * DIM;                    // 12.6 MB
  f16* WoT = ws + off; off += (size_t)DIM * DIM;                      // 2 MB
  f16* oh  = ws + off; off += (size_t)SEQ * DIM;                      // 4 MB
  f16* pO  = ws + off; off += (size_t)NH * 16 * MAXSPLIT * 128 * 64;  // 25.2 MB
  float* pML = (float*)(ws + off); off += (size_t)NH * 16 * MAXSPLIT * 256 * 2; // 1.6 MB
  // total ~75 MB of workspace

  k_cast_x<<<(SEQ * DIM) / 1024, 256, 0, stream>>>(x, xh);
  k_tcast<<<dim3(NCOLS / 64, DIM / 64), 256, 0, stream>>>(Wq, WqT, DIM, NCOLS);
  k_tcast<<<dim3(DIM / 64, DIM / 64), 256, 0, stream>>>(Wo, WoT, DIM, DIM);
  k_gemm_qkv<<<dim3(NCOLS / 128, SEQ / 128), 256, 0, stream>>>(xh, WqT, q6);
  k_flash<<<NH * SPLITS_PER_HEAD, 256, 0, stream>>>(q6, pO, pML);
  k_merge<<<NH * 16, 256, 0, stream>>>(pO, pML, oh);
  k_gemm_out<<<dim3(DIM / 128, SEQ / 128), 256, 0, stream>>>(oh, WoT, out);
}

// Round 9
// 522.405 us; speedup vs baseline: 2.9903x; 1.4139x over previous
//
#include <hip/hip_runtime.h>
#include <math.h>

typedef _Float16 f16;
typedef _Float16 f16x4 __attribute__((ext_vector_type(4)));
typedef _Float16 f16x8 __attribute__((ext_vector_type(8)));
typedef float f32x4 __attribute__((ext_vector_type(4)));

#define SEQ   2048
#define DIM   1024
#define NH    16
#define DH    64
#define NCOLS 6144
#define NHSD  (NH*SEQ*DH)   /* 2,097,152 elements per qkv sub-tensor */
#define SPLITS_PER_HEAD 40  /* sum of NS[] over I=0..15 */
#define NTILE 136           /* lk tiles per head: (K,J) with J>=K */

__device__ __forceinline__ int nsplits(int I) {
  const int NS[16] = {1,1,1,1,1,1,2,2,2,3,3,3,4,4,5,6};
  return NS[I];
}

// ------------- transpose + cast: out[c][r] = (f16) in[r][c], in is R x C -------------
__global__ __launch_bounds__(256) void k_tcast(const float* __restrict__ in, f16* __restrict__ out,
                                               int R, int C) {
  __shared__ f16 t[64 * 66];
  int bc = blockIdx.x, br = blockIdx.y;
  for (int it = 0; it < 16; ++it) {
    int idx = it * 256 + threadIdx.x;
    int r = idx >> 6, c = idx & 63;
    t[r * 66 + c] = (f16)in[(size_t)(br * 64 + r) * C + bc * 64 + c];
  }
  __syncthreads();
  for (int it = 0; it < 16; ++it) {
    int idx = it * 256 + threadIdx.x;
    int oc = idx >> 6, orr = idx & 63;
    out[(size_t)(bc * 64 + oc) * R + br * 64 + orr] = t[orr * 66 + oc];
  }
}

// ---------------- qkv GEMM: x[2048,1024](f32, cast in staging) @ WqT[6144,1024]^T ----------------
__global__ __launch_bounds__(256) void k_gemm_qkv(const float* __restrict__ x, const f16* __restrict__ B,
                                                  f16* __restrict__ q6) {
  __shared__ f16 sa[128 * 72];
  __shared__ f16 sb[128 * 72];
  int bx = blockIdx.x, by = blockIdx.y;
  int tid = threadIdx.x, w = tid >> 6, l = tid & 63, q = l >> 4, c = l & 15;
  f32x4 acc[2][8];
  const f32x4 zf = {0.f, 0.f, 0.f, 0.f};
  for (int i = 0; i < 2; ++i) for (int j = 0; j < 8; ++j) acc[i][j] = zf;

  for (int kt = 0; kt < DIM / 64; ++kt) {
    __syncthreads();
#pragma unroll
    for (int it = 0; it < 4; ++it) {
      int idx = it * 256 + tid; int r = idx >> 3, ch = idx & 7;
      const float* ap = x + (size_t)(by * 128 + r) * DIM + kt * 64 + ch * 8;
      float4 lo = *(const float4*)(ap);
      float4 hi = *(const float4*)(ap + 4);
      f16x8 h;
      h[0] = (f16)lo.x; h[1] = (f16)lo.y; h[2] = (f16)lo.z; h[3] = (f16)lo.w;
      h[4] = (f16)hi.x; h[5] = (f16)hi.y; h[6] = (f16)hi.z; h[7] = (f16)hi.w;
      *(f16x8*)(sa + r * 72 + ch * 8) = h;
      *(float4*)(sb + r * 72 + ch * 8) = *(const float4*)(B + (size_t)(bx * 128 + r) * DIM + kt * 64 + ch * 8);
    }
    __syncthreads();
#pragma unroll
    for (int ks = 0; ks < 2; ++ks) {
      f16x8 af[2], bf[8];
#pragma unroll
      for (int tr = 0; tr < 2; ++tr) af[tr] = *(const f16x8*)(sa + (w * 32 + tr * 16 + c) * 72 + ks * 32 + q * 8);
#pragma unroll
      for (int tc = 0; tc < 8; ++tc) bf[tc] = *(const f16x8*)(sb + (tc * 16 + c) * 72 + ks * 32 + q * 8);
#pragma unroll
      for (int tr = 0; tr < 2; ++tr)
#pragma unroll
        for (int tc = 0; tc < 8; ++tc)
          acc[tr][tc] = __builtin_amdgcn_mfma_f32_16x16x32_f16(af[tr], bf[tc], acc[tr][tc], 0, 0, 0);
    }
  }
  // epilogue: scatter into qu(0) ku(1) vu(2) qc(3) kc(4) vcT(5); scale qu,qc by dh^-0.5
#pragma unroll
  for (int tr = 0; tr < 2; ++tr)
#pragma unroll
    for (int tc = 0; tc < 8; ++tc)
#pragma unroll
      for (int r = 0; r < 4; ++r) {
        int row = by * 128 + w * 32 + tr * 16 + q * 4 + r;
        int col = bx * 128 + tc * 16 + c;
        float v = acc[tr][tc][r];
        int t = col >> 10, head = (col >> 6) & 15, dh = col & 63;
        if (t == 0 || t == 3) v *= 0.125f;
        if (t == 5) q6[(size_t)5 * NHSD + (size_t)(head * DH + dh) * SEQ + row] = (f16)v;
        else        q6[(size_t)t * NHSD + (size_t)(head * SEQ + row) * DH + dh] = (f16)v;
      }
}

// ---------------- lk tile producer: lk(K,J) = sigmoid(qu_s K-rows @ ku J-rows^T), strict j>k ----------------
// Computes each of the 2176 distinct tiles ONCE (R8's flash recomputed them 6x chip-wide, paying
// 64 exp + 64 rcp per lane per step — the dominant VALU phase). Output stored in B-FRAG ORDER:
// chunk ch = ks*512 + rb*64 + lane ; holds lk[rb*16 + (lane&15)][ks*32 + (lane>>4)*8 + 0..7],
// so the consumer reads bf frags straight from global, perfectly coalesced (1KB/instr).
__global__ __launch_bounds__(256) void k_lk(const f16* __restrict__ q6, f16* __restrict__ lkT) {
  __shared__ f16 st[128 * 128];
  int head = blockIdx.x / NTILE;
  int p = blockIdx.x % NTILE;
  int K = 0, off = 0;
  while (off + (16 - K) <= p) { off += 16 - K; ++K; }
  int J = K + (p - off);
  const f16* qu = q6 + (size_t)0 * NHSD + (size_t)head * SEQ * DH;   // pre-scaled by dh^-0.5
  const f16* ku = q6 + (size_t)1 * NHSD + (size_t)head * SEQ * DH;
  int tid = threadIdx.x, w = tid >> 6, l = tid & 63, q = l >> 4, c = l & 15;
  const f32x4 zf = {0.f, 0.f, 0.f, 0.f};
  f32x4 tacc[2][8];
  for (int tr = 0; tr < 2; ++tr) for (int tc = 0; tc < 8; ++tc) tacc[tr][tc] = zf;
#pragma unroll
  for (int ks = 0; ks < 2; ++ks) {
    f16x8 aq[2], bf[8];
#pragma unroll
    for (int tr = 0; tr < 2; ++tr)
      aq[tr] = *(const f16x8*)(qu + (size_t)(K * 128 + w * 32 + tr * 16 + c) * DH + ks * 32 + q * 8);
#pragma unroll
    for (int tc = 0; tc < 8; ++tc)
      bf[tc] = *(const f16x8*)(ku + (size_t)(J * 128 + tc * 16 + c) * DH + ks * 32 + q * 8);
#pragma unroll
    for (int tr = 0; tr < 2; ++tr)
#pragma unroll
      for (int tc = 0; tc < 8; ++tc)
        tacc[tr][tc] = __builtin_amdgcn_mfma_f32_16x16x32_f16(aq[tr], bf[tc], tacc[tr][tc], 0, 0, 0);
  }
  // epilogue: sigmoid + strict mask -> LDS row-major (swizzled), own rows
#pragma unroll
  for (int tr = 0; tr < 2; ++tr)
#pragma unroll
    for (int tc = 0; tc < 8; ++tc)
#pragma unroll
      for (int r = 0; r < 4; ++r) {
        int row = w * 32 + tr * 16 + q * 4 + r;
        int col = tc * 16 + c;
        int kg = K * 128 + row, jg = J * 128 + col;
        float v = tacc[tr][tc][r];
        f16 ov = (jg > kg) ? (f16)__builtin_amdgcn_rcpf(1.f + __expf(-v)) : (f16)(0.f);
        st[(row << 7) + (((col >> 3) ^ (row & 15)) << 3) + (col & 7)] = ov;
      }
  __syncthreads();
  // re-read in frag order, write 16B-coalesced
  f16* dst = lkT + ((size_t)blockIdx.x << 14);
#pragma unroll
  for (int i = 0; i < 8; ++i) {
    int ch = i * 256 + tid;
    int ks = ch >> 9, rb = (ch >> 6) & 7, ln = ch & 63;
    int qq = ln >> 4, cc = ln & 15;
    int row = rb * 16 + cc, cchunk = ks * 4 + qq;
    f16x8 v = *(const f16x8*)(st + (row << 7) + ((cchunk ^ (row & 15)) << 3));
    *(f16x8*)(dst + (size_t)ch * 8) = v;
  }
}

// ---------------- split-K fused flash (R9: BARRIER-FREE, lk from pre-made frag tiles) ----------------
// 256 threads, 4 waves x 32 rows, grid 640 = (head XCD-swizzled, rsub in [0,40)), NS splits as R8.
// sa holds t1 then P — written/read by OWN-wave rows only, so with lk read directly from global
// (B-frag layout) there is NO __syncthreads() anywhere: waves stream independently, and the
// compiler can pipeline loads across J (no barrier drain — the R8 step's 2 barriers + sigmoid
// epilogue + ku loads + 32 MFMAs are all gone).
__global__ __launch_bounds__(256, 1) void k_flash(const f16* __restrict__ q6, const f16* __restrict__ lkT,
                                                  f16* __restrict__ pO, float* __restrict__ pML) {
  __shared__ f16 sa[128 * 128];
  int bid = blockIdx.x;
  int head = ((bid & 7) << 1) | ((bid >> 3) & 1);
  int rsub = bid >> 4;          // [0,40)
  int I = 0, s = 0;
  {
    int acc = 0;
    for (int ii = 0; ii < 16; ++ii) {
      int si = nsplits(ii);
      if (rsub >= acc && rsub < acc + si) { I = ii; s = rsub - acc; }
      acc += si;
    }
  }
  int S_ = nsplits(I);
  int C = (I + 1) * (I + 2) / 2;
  int K0 = 16, K1 = 0;
  {
    int p = 0;
    for (int K = 0; K <= I; ++K) {
      int cost = I - K + 1;
      int seg = ((2 * p + cost) * S_) / (2 * C);
      if (seg == s) { if (K < K0) K0 = K; K1 = K + 1; }
      p += cost;
    }
  }

  const f16* vu = q6 + (size_t)2 * NHSD + (size_t)head * SEQ * DH;
  const f16* qc = q6 + (size_t)3 * NHSD + (size_t)head * SEQ * DH;   // pre-scaled by dh^-0.5
  const f16* kc = q6 + (size_t)4 * NHSD + (size_t)head * SEQ * DH;
  const f16* vt = q6 + (size_t)5 * NHSD + (size_t)head * DH * SEQ;   // vc transposed [64][2048]
  int tid = threadIdx.x, w = tid >> 6, l = tid & 63, q = l >> 4, c = l & 15;

  // qc_s(I) A-frags: every t1 tile + the Sc MFMA
  f16x8 a_qc[2][2];
#pragma unroll
  for (int tr = 0; tr < 2; ++tr)
#pragma unroll
    for (int ks = 0; ks < 2; ++ks)
      a_qc[tr][ks] = *(const f16x8*)(qc + (size_t)(I * 128 + w * 32 + tr * 16 + c) * DH + ks * 32 + q * 8);

  f32x4 su[2][8], tacc[2][8], oacc[2][4];
  float m_i[2][4], l_i[2][4];
  const f32x4 zf = {0.f, 0.f, 0.f, 0.f};
  for (int tr = 0; tr < 2; ++tr) for (int tv = 0; tv < 4; ++tv) oacc[tr][tv] = zf;
  for (int tr = 0; tr < 2; ++tr) for (int r = 0; r < 4; ++r) { m_i[tr][r] = -INFINITY; l_i[tr][r] = 0.f; }

  for (int K = K0; K < K1; ++K) {
    int offK = 16 * K - (K * (K - 1)) / 2;   // lk tile row offset for this K
#pragma unroll
    for (int tr = 0; tr < 2; ++tr) for (int tc = 0; tc < 8; ++tc) su[tr][tc] = zf;

    for (int J = K; J <= I; ++J) {
      const f16* lt = lkT + ((size_t)(head * NTILE + offK + (J - K)) << 14);

      // ---- t1(I,J) tile: qc_s(I) @ vu(J)^T, keep j<=i -> sa (own rows; no barrier) ----
      for (int tr = 0; tr < 2; ++tr) for (int tc = 0; tc < 8; ++tc) tacc[tr][tc] = zf;
#pragma unroll
      for (int ks = 0; ks < 2; ++ks) {
        f16x8 bf[8];
#pragma unroll
        for (int tc = 0; tc < 8; ++tc)
          bf[tc] = *(const f16x8*)(vu + (size_t)(J * 128 + tc * 16 + c) * DH + ks * 32 + q * 8);
#pragma unroll
        for (int tr = 0; tr < 2; ++tr)
#pragma unroll
          for (int tc = 0; tc < 8; ++tc)
            tacc[tr][tc] = __builtin_amdgcn_mfma_f32_16x16x32_f16(a_qc[tr][ks], bf[tc], tacc[tr][tc], 0, 0, 0);
      }
#pragma unroll
      for (int tr = 0; tr < 2; ++tr)
#pragma unroll
        for (int tc = 0; tc < 8; ++tc)
#pragma unroll
          for (int r = 0; r < 4; ++r) {
            int row = w * 32 + tr * 16 + q * 4 + r;
            int col = tc * 16 + c;
            int ig = I * 128 + row, jg = J * 128 + col;
            float v = tacc[tr][tc][r];
            f16 ov = (jg <= ig) ? (f16)v : (f16)(0.f);
            sa[(row << 7) + (((col >> 3) ^ (row & 15)) << 3) + (col & 7)] = ov;
          }

      // ---- Su += t1 @ lk^T : af from own sa rows, bf straight from global frag tiles ----
#pragma unroll
      for (int ks = 0; ks < 4; ++ks) {
        int ck = ks * 4 + q;
        f16x8 af[2], bf[8];
#pragma unroll
        for (int tr = 0; tr < 2; ++tr)
          af[tr] = *(const f16x8*)(sa + ((w * 32 + tr * 16 + c) << 7) + ((ck ^ c) << 3));
#pragma unroll
        for (int tc = 0; tc < 8; ++tc)
          bf[tc] = *(const f16x8*)(lt + (size_t)(ks * 512 + tc * 64 + l) * 8);
#pragma unroll
        for (int tr = 0; tr < 2; ++tr)
#pragma unroll
          for (int tc = 0; tc < 8; ++tc)
            su[tr][tc] = __builtin_amdgcn_mfma_f32_16x16x32_f16(af[tr], bf[tc], su[tr][tc], 0, 0, 0);
      }
    }

    // scores = Sc - silu(Su)
#pragma unroll
    for (int tr = 0; tr < 2; ++tr)
#pragma unroll
      for (int tc = 0; tc < 8; ++tc)
#pragma unroll
        for (int r = 0; r < 4; ++r) {
          float v = su[tr][tc][r];
          su[tr][tc][r] = -v * __builtin_amdgcn_rcpf(1.f + __expf(-v));
        }
#pragma unroll
    for (int ks = 0; ks < 2; ++ks) {
      f16x8 bk[8];
#pragma unroll
      for (int tc = 0; tc < 8; ++tc)
        bk[tc] = *(const f16x8*)(kc + (size_t)(K * 128 + tc * 16 + c) * DH + ks * 32 + q * 8);
#pragma unroll
      for (int tr = 0; tr < 2; ++tr)
#pragma unroll
        for (int tc = 0; tc < 8; ++tc)
          su[tr][tc] = __builtin_amdgcn_mfma_f32_16x16x32_f16(a_qc[tr][ks], bk[tc], su[tr][tc], 0, 0, 0);
    }
    if (K == I) {   // strict causal mask inside the diagonal block
#pragma unroll
      for (int tr = 0; tr < 2; ++tr)
#pragma unroll
        for (int tc = 0; tc < 8; ++tc)
#pragma unroll
          for (int r = 0; r < 4; ++r) {
            int rg = w * 32 + tr * 16 + q * 4 + r;
            int cg = tc * 16 + c;
            if (cg > rg) su[tr][tc][r] = -INFINITY;
          }
    }
    // online softmax (per-row, shuffle across low-4 lane bits)
#pragma unroll
    for (int tr = 0; tr < 2; ++tr)
#pragma unroll
      for (int r = 0; r < 4; ++r) {
        float mx = su[tr][0][r];
#pragma unroll
        for (int tc = 1; tc < 8; ++tc) mx = fmaxf(mx, su[tr][tc][r]);
        mx = fmaxf(mx, __shfl_xor(mx, 1)); mx = fmaxf(mx, __shfl_xor(mx, 2));
        mx = fmaxf(mx, __shfl_xor(mx, 4)); mx = fmaxf(mx, __shfl_xor(mx, 8));
        float mnew  = fmaxf(m_i[tr][r], mx);
        float alpha = __expf(m_i[tr][r] - mnew);
        float ssum = 0.f;
#pragma unroll
        for (int tc = 0; tc < 8; ++tc) {
          float pp = __expf(su[tr][tc][r] - mnew);
          su[tr][tc][r] = pp;
          ssum += pp;
        }
        ssum += __shfl_xor(ssum, 1); ssum += __shfl_xor(ssum, 2);
        ssum += __shfl_xor(ssum, 4); ssum += __shfl_xor(ssum, 8);
        l_i[tr][r] = l_i[tr][r] * alpha + ssum;
        m_i[tr][r] = mnew;
#pragma unroll
        for (int tv = 0; tv < 4; ++tv) oacc[tr][tv][r] *= alpha;
      }
    // P -> sa (own rows; no barrier)
#pragma unroll
    for (int tr = 0; tr < 2; ++tr)
#pragma unroll
      for (int tc = 0; tc < 8; ++tc)
#pragma unroll
        for (int r = 0; r < 4; ++r) {
          int row = w * 32 + tr * 16 + q * 4 + r;
          int col = tc * 16 + c;
          sa[(row << 7) + (((col >> 3) ^ (row & 15)) << 3) + (col & 7)] = (f16)su[tr][tc][r];
        }
    // PV: A = P (own sa rows), B = vcT from global
#pragma unroll
    for (int ks = 0; ks < 4; ++ks) {
      int ck = ks * 4 + q;
      f16x8 af[2], bv[4];
#pragma unroll
      for (int tr = 0; tr < 2; ++tr)
        af[tr] = *(const f16x8*)(sa + ((w * 32 + tr * 16 + c) << 7) + ((ck ^ c) << 3));
#pragma unroll
      for (int tv = 0; tv < 4; ++tv)
        bv[tv] = *(const f16x8*)(vt + (size_t)(tv * 16 + c) * SEQ + K * 128 + ks * 32 + q * 8);
#pragma unroll
      for (int tr = 0; tr < 2; ++tr)
#pragma unroll
        for (int tv = 0; tv < 4; ++tv)
          oacc[tr][tv] = __builtin_amdgcn_mfma_f32_16x16x32_f16(af[tr], bv[tv], oacc[tr][tv], 0, 0, 0);
    }
  }

  // ---- unnormalized partial, compact slot = head*40 + rsub ----
  int slot = head * SPLITS_PER_HEAD + rsub;
  f16* po = pO + (size_t)slot * (128 * 64);
  float* pml = pML + (size_t)slot * 256;
  if (c == 0) {
#pragma unroll
    for (int tr = 0; tr < 2; ++tr)
#pragma unroll
      for (int r = 0; r < 4; ++r) {
        int row = w * 32 + tr * 16 + q * 4 + r;
        pml[row] = m_i[tr][r];
        pml[128 + row] = l_i[tr][r];
      }
  }
#pragma unroll
  for (int tr = 0; tr < 2; ++tr)
#pragma unroll
    for (int tv = 0; tv < 4; ++tv)
#pragma unroll
      for (int r = 0; r < 4; ++r) {
        int row = w * 32 + tr * 16 + q * 4 + r;
        int col = tv * 16 + c;
        po[row * 64 + col] = (f16)oacc[tr][tv][r];
      }
}

// ---------------- merge partials -> oh [2048][1024] f16 ----------------
__global__ __launch_bounds__(256) void k_merge(const f16* __restrict__ pO, const float* __restrict__ pML,
                                               f16* __restrict__ oh) {
  int head = blockIdx.x >> 4, I = blockIdx.x & 15;
  int S_ = nsplits(I);
  int base_rsub = 0;
  for (int ii = 0; ii < I; ++ii) base_rsub += nsplits(ii);
  int tid = threadIdx.x;
  int row = tid >> 1, half = tid & 1;
  int base = head * SPLITS_PER_HEAD + base_rsub;
  float m[6], lv[6];
  float mstar = -INFINITY;
#pragma unroll
  for (int s = 0; s < 6; ++s)
    if (s < S_) {
      m[s] = pML[(size_t)(base + s) * 256 + row];
      lv[s] = pML[(size_t)(base + s) * 256 + 128 + row];
      mstar = fmaxf(mstar, m[s]);
    }
  float wt[6];
  float lsum = 0.f;
#pragma unroll
  for (int s = 0; s < 6; ++s)
    if (s < S_) {
      wt[s] = __expf(m[s] - mstar);
      lsum += lv[s] * wt[s];
    }
  float rinv = __builtin_amdgcn_rcpf(lsum);
#pragma unroll
  for (int cc = 0; cc < 32; cc += 8) {
    float acc[8] = {0.f, 0.f, 0.f, 0.f, 0.f, 0.f, 0.f, 0.f};
#pragma unroll
    for (int s = 0; s < 6; ++s)
      if (s < S_) {
        f16x8 v = *(const f16x8*)(pO + (size_t)(base + s) * 8192 + row * 64 + half * 32 + cc);
#pragma unroll
        for (int e = 0; e < 8; ++e) acc[e] += wt[s] * (float)v[e];
      }
    f16x8 o;
#pragma unroll
    for (int e = 0; e < 8; ++e) o[e] = (f16)(acc[e] * rinv);
    *(f16x8*)(oh + (size_t)(I * 128 + row) * DIM + head * 64 + half * 32 + cc) = o;
  }
}

// ---------------- final GEMM: oh[2048,1024] @ WoT[1024,1024]^T -> fp32 out ----------------
__global__ __launch_bounds__(256) void k_gemm_out(const f16* __restrict__ A, const f16* __restrict__ B,
                                                  float* __restrict__ out) {
  __shared__ f16 sa[128 * 72];
  __shared__ f16 sb[128 * 72];
  int bx = blockIdx.x, by = blockIdx.y;
  int tid = threadIdx.x, w = tid >> 6, l = tid & 63, q = l >> 4, c = l & 15;
  f32x4 acc[2][8];
  const f32x4 zf = {0.f, 0.f, 0.f, 0.f};
  for (int i = 0; i < 2; ++i) for (int j = 0; j < 8; ++j) acc[i][j] = zf;
  for (int kt = 0; kt < DIM / 64; ++kt) {
    __syncthreads();
#pragma unroll
    for (int it = 0; it < 4; ++it) {
      int idx = it * 256 + tid; int r = idx >> 3, ch = idx & 7;
      *(float4*)(sa + r * 72 + ch * 8) = *(const float4*)(A + (size_t)(by * 128 + r) * DIM + kt * 64 + ch * 8);
      *(float4*)(sb + r * 72 + ch * 8) = *(const float4*)(B + (size_t)(bx * 128 + r) * DIM + kt * 64 + ch * 8);
    }
    __syncthreads();
#pragma unroll
    for (int ks = 0; ks < 2; ++ks) {
      f16x8 af[2], bf[8];
#pragma unroll
      for (int tr = 0; tr < 2; ++tr) af[tr] = *(const f16x8*)(sa + (w * 32 + tr * 16 + c) * 72 + ks * 32 + q * 8);
#pragma unroll
      for (int tc = 0; tc < 8; ++tc) bf[tc] = *(const f16x8*)(sb + (tc * 16 + c) * 72 + ks * 32 + q * 8);
#pragma unroll
      for (int tr = 0; tr < 2; ++tr)
#pragma unroll
        for (int tc = 0; tc < 8; ++tc)
          acc[tr][tc] = __builtin_amdgcn_mfma_f32_16x16x32_f16(af[tr], bf[tc], acc[tr][tc], 0, 0, 0);
    }
  }
#pragma unroll
  for (int tr = 0; tr < 2; ++tr)
#pragma unroll
    for (int tc = 0; tc < 8; ++tc)
#pragma unroll
      for (int r = 0; r < 4; ++r) {
        int row = by * 128 + w * 32 + tr * 16 + q * 4 + r;
        int col = bx * 128 + tc * 16 + c;
        out[(size_t)row * DIM + col] = acc[tr][tc][r];
      }
}

extern "C" void kernel_launch(void* const* d_in, const int* in_sizes, int n_in,
                              void* d_out, int out_size, void* d_ws, size_t ws_size,
                              hipStream_t stream) {
  const float* x  = (const float*)d_in[0];
  const float* Wq = (const float*)d_in[1];
  const float* Wo = (const float*)d_in[2];
  float* out = (float*)d_out;

  f16* ws = (f16*)d_ws;
  size_t off = 0;
  f16* q6  = ws + off; off += (size_t)6 * NHSD;                        // 25.2 MB
  f16* WqT = ws + off; off += (size_t)NCOLS * DIM;                     // 12.6 MB
  f16* WoT = ws + off; off += (size_t)DIM * DIM;                       // 2.1 MB
  f16* oh  = ws + off; off += (size_t)SEQ * DIM;                       // 4.2 MB
  f16* pO  = ws + off; off += (size_t)NH * SPLITS_PER_HEAD * 128 * 64; // 10.5 MB
  f16* lkT = ws + off; off += (size_t)NH * NTILE * 128 * 128;          // 71.3 MB
  float* pML = (float*)(ws + off); off += (size_t)NH * SPLITS_PER_HEAD * 256 * 2; // 0.66 MB
  // total ~126.5 MB of workspace

  k_tcast<<<dim3(NCOLS / 64, DIM / 64), 256, 0, stream>>>(Wq, WqT, DIM, NCOLS);
  k_tcast<<<dim3(DIM / 64, DIM / 64), 256, 0, stream>>>(Wo, WoT, DIM, DIM);
  k_gemm_qkv<<<dim3(NCOLS / 128, SEQ / 128), 256, 0, stream>>>(x, WqT, q6);
  k_lk<<<NH * NTILE, 256, 0, stream>>>(q6, lkT);
  k_flash<<<NH * SPLITS_PER_HEAD, 256, 0, stream>>>(q6, lkT, pO, pML);
  k_merge<<<NH * 16, 256, 0, stream>>>(pO, pML, oh);
  k_gemm_out<<<dim3(DIM / 128, SEQ / 128), 256, 0, stream>>>(oh, WoT, out);
}

// Round 10
// 472.900 us; speedup vs baseline: 3.3033x; 1.1047x over previous
//
#include <hip/hip_runtime.h>
#include <math.h>

typedef _Float16 f16;
typedef _Float16 f16x4 __attribute__((ext_vector_type(4)));
typedef _Float16 f16x8 __attribute__((ext_vector_type(8)));
typedef float f32x4 __attribute__((ext_vector_type(4)));

#define SEQ   2048
#define DIM   1024
#define NH    16
#define DH    64
#define NCOLS 6144
#define NHSD  (NH*SEQ*DH)   /* 2,097,152 elements per qkv sub-tensor */
#define SPLITS_PER_HEAD 40  /* sum of NS[] over I=0..15 */
#define NTILE 136           /* tiles per head per tensor (triangular) */

__device__ __forceinline__ int nsplits(int I) {
  const int NS[16] = {1,1,1,1,1,1,2,2,2,3,3,3,4,4,5,6};
  return NS[I];
}

// ------------- transpose + cast: out[c][r] = (f16) in[r][c], in is R x C -------------
__global__ __launch_bounds__(256) void k_tcast(const float* __restrict__ in, f16* __restrict__ out,
                                               int R, int C) {
  __shared__ f16 t[64 * 66];
  int bc = blockIdx.x, br = blockIdx.y;
  for (int it = 0; it < 16; ++it) {
    int idx = it * 256 + threadIdx.x;
    int r = idx >> 6, c = idx & 63;
    t[r * 66 + c] = (f16)in[(size_t)(br * 64 + r) * C + bc * 64 + c];
  }
  __syncthreads();
  for (int it = 0; it < 16; ++it) {
    int idx = it * 256 + threadIdx.x;
    int oc = idx >> 6, orr = idx & 63;
    out[(size_t)(bc * 64 + oc) * R + br * 64 + orr] = t[orr * 66 + oc];
  }
}

// ---------------- qkv GEMM: x[2048,1024](f32, cast in staging) @ WqT[6144,1024]^T ----------------
__global__ __launch_bounds__(256) void k_gemm_qkv(const float* __restrict__ x, const f16* __restrict__ B,
                                                  f16* __restrict__ q6) {
  __shared__ f16 sa[128 * 72];
  __shared__ f16 sb[128 * 72];
  int bx = blockIdx.x, by = blockIdx.y;
  int tid = threadIdx.x, w = tid >> 6, l = tid & 63, q = l >> 4, c = l & 15;
  f32x4 acc[2][8];
  const f32x4 zf = {0.f, 0.f, 0.f, 0.f};
  for (int i = 0; i < 2; ++i) for (int j = 0; j < 8; ++j) acc[i][j] = zf;

  for (int kt = 0; kt < DIM / 64; ++kt) {
    __syncthreads();
#pragma unroll
    for (int it = 0; it < 4; ++it) {
      int idx = it * 256 + tid; int r = idx >> 3, ch = idx & 7;
      const float* ap = x + (size_t)(by * 128 + r) * DIM + kt * 64 + ch * 8;
      float4 lo = *(const float4*)(ap);
      float4 hi = *(const float4*)(ap + 4);
      f16x8 h;
      h[0] = (f16)lo.x; h[1] = (f16)lo.y; h[2] = (f16)lo.z; h[3] = (f16)lo.w;
      h[4] = (f16)hi.x; h[5] = (f16)hi.y; h[6] = (f16)hi.z; h[7] = (f16)hi.w;
      *(f16x8*)(sa + r * 72 + ch * 8) = h;
      *(float4*)(sb + r * 72 + ch * 8) = *(const float4*)(B + (size_t)(bx * 128 + r) * DIM + kt * 64 + ch * 8);
    }
    __syncthreads();
#pragma unroll
    for (int ks = 0; ks < 2; ++ks) {
      f16x8 af[2], bf[8];
#pragma unroll
      for (int tr = 0; tr < 2; ++tr) af[tr] = *(const f16x8*)(sa + (w * 32 + tr * 16 + c) * 72 + ks * 32 + q * 8);
#pragma unroll
      for (int tc = 0; tc < 8; ++tc) bf[tc] = *(const f16x8*)(sb + (tc * 16 + c) * 72 + ks * 32 + q * 8);
#pragma unroll
      for (int tr = 0; tr < 2; ++tr)
#pragma unroll
        for (int tc = 0; tc < 8; ++tc)
          acc[tr][tc] = __builtin_amdgcn_mfma_f32_16x16x32_f16(af[tr], bf[tc], acc[tr][tc], 0, 0, 0);
    }
  }
  // epilogue: scatter into qu(0) ku(1) vu(2) qc(3) kc(4) vcT(5); scale qu,qc by dh^-0.5
#pragma unroll
  for (int tr = 0; tr < 2; ++tr)
#pragma unroll
    for (int tc = 0; tc < 8; ++tc)
#pragma unroll
      for (int r = 0; r < 4; ++r) {
        int row = by * 128 + w * 32 + tr * 16 + q * 4 + r;
        int col = bx * 128 + tc * 16 + c;
        float v = acc[tr][tc][r];
        int t = col >> 10, head = (col >> 6) & 15, dh = col & 63;
        if (t == 0 || t == 3) v *= 0.125f;
        if (t == 5) q6[(size_t)5 * NHSD + (size_t)(head * DH + dh) * SEQ + row] = (f16)v;
        else        q6[(size_t)t * NHSD + (size_t)(head * SEQ + row) * DH + dh] = (f16)v;
      }
}

// ---------------- t1 + lk tile producer (each distinct tile computed ONCE, stored frag-ordered) ----------------
// grid NH*272: p<136 -> t1(I,J)=qc_s(I)@vu(J)^T masked j<=i (A-frag order); p>=136 -> lk(K,J)=
// sigmoid(qu_s(K)@ku(J)^T) strict j>k (B-frag order). A-frag A[m][k] (m=lane&15,k=(lane>>4)*8+j)
// and B-frag B[n][k] have IDENTICAL lane->(row,k) maps, so one LDS-reorder epilogue serves both.
// Chunk (ck,rb) of a 128(row)x128(k) tile sits at ((ck*8+rb)*64+lane)*8 — consumer loads are
// 16B/lane fully-coalesced (1KB/instr).
__global__ __launch_bounds__(256) void k_t1lk(const f16* __restrict__ q6, f16* __restrict__ t1T,
                                              f16* __restrict__ lkT) {
  __shared__ f16 st[128 * 128];
  int head = blockIdx.x / 272;
  int p = blockIdx.x % 272;
  bool is_lk = (p >= 136);
  int RB, CB;        // row-block (i or k), col-block (j)
  f16* dst;
  if (is_lk) {
    int p2 = p - 136;
    int K = 0, off = 0;
    while (off + (16 - K) <= p2) { off += 16 - K; ++K; }
    RB = K; CB = K + (p2 - off);
    dst = lkT + ((size_t)(head * NTILE + p2) << 14);
  } else {
    int I = 0;
    while ((I + 1) * (I + 2) / 2 <= p) ++I;
    RB = I; CB = p - I * (I + 1) / 2;
    dst = t1T + ((size_t)(head * NTILE + p) << 14);
  }
  const f16* Ah = q6 + (size_t)(is_lk ? 0 : 3) * NHSD + (size_t)head * SEQ * DH;  // qu_s / qc_s
  const f16* Bh = q6 + (size_t)(is_lk ? 1 : 2) * NHSD + (size_t)head * SEQ * DH;  // ku / vu
  int tid = threadIdx.x, w = tid >> 6, l = tid & 63, q = l >> 4, c = l & 15;
  const f32x4 zf = {0.f, 0.f, 0.f, 0.f};
  f32x4 tacc[2][8];
  for (int tr = 0; tr < 2; ++tr) for (int tc = 0; tc < 8; ++tc) tacc[tr][tc] = zf;
#pragma unroll
  for (int ks = 0; ks < 2; ++ks) {
    f16x8 aq[2], bf[8];
#pragma unroll
    for (int tr = 0; tr < 2; ++tr)
      aq[tr] = *(const f16x8*)(Ah + (size_t)(RB * 128 + w * 32 + tr * 16 + c) * DH + ks * 32 + q * 8);
#pragma unroll
    for (int tc = 0; tc < 8; ++tc)
      bf[tc] = *(const f16x8*)(Bh + (size_t)(CB * 128 + tc * 16 + c) * DH + ks * 32 + q * 8);
#pragma unroll
    for (int tr = 0; tr < 2; ++tr)
#pragma unroll
      for (int tc = 0; tc < 8; ++tc)
        tacc[tr][tc] = __builtin_amdgcn_mfma_f32_16x16x32_f16(aq[tr], bf[tc], tacc[tr][tc], 0, 0, 0);
  }
  // epilogue: mask (+sigmoid for lk) -> LDS row-major swizzled, own rows
#pragma unroll
  for (int tr = 0; tr < 2; ++tr)
#pragma unroll
    for (int tc = 0; tc < 8; ++tc)
#pragma unroll
      for (int r = 0; r < 4; ++r) {
        int row = w * 32 + tr * 16 + q * 4 + r;
        int col = tc * 16 + c;
        int rg = RB * 128 + row, cg = CB * 128 + col;
        float v = tacc[tr][tc][r];
        f16 ov;
        if (is_lk) ov = (cg > rg) ? (f16)__builtin_amdgcn_rcpf(1.f + __expf(-v)) : (f16)(0.f);
        else       ov = (cg <= rg) ? (f16)v : (f16)(0.f);
        st[(row << 7) + (((col >> 3) ^ (row & 15)) << 3) + (col & 7)] = ov;
      }
  __syncthreads();
  // re-read in frag order, write 16B-coalesced
#pragma unroll
  for (int i = 0; i < 8; ++i) {
    int ch = i * 256 + tid;
    int ks = ch >> 9, rb = (ch >> 6) & 7, ln = ch & 63;
    int qq = ln >> 4, cc = ln & 15;
    int row = rb * 16 + cc, cchunk = ks * 4 + qq;
    f16x8 v = *(const f16x8*)(st + (row << 7) + ((cchunk ^ (row & 15)) << 3));
    *(f16x8*)(dst + (size_t)ch * 8) = v;
  }
}

// ---------------- split-K flash (R10: Su = pure streaming MFMA from pre-made frag tiles) ----------------
// 256 threads, 4 waves x 32 rows, grid 640 (XCD-swizzled heads, NS splits). The J-loop now does
// ONLY: 8 af loads (t1T) + 32 bf loads (lkT, wave-identical -> L2 broadcast) + 64 MFMAs.
// No LDS, no transcendentals, no barriers in the hot loop — t1's 6x chip-wide recompute (16 MFMA +
// ~200 VALU + 64 ds_write per step, R9's dominant cost) is gone. sa (32KB) only holds P for PV.
__global__ __launch_bounds__(256, 1) void k_flash(const f16* __restrict__ q6, const f16* __restrict__ t1T,
                                                  const f16* __restrict__ lkT,
                                                  f16* __restrict__ pO, float* __restrict__ pML) {
  __shared__ f16 sa[128 * 128];
  int bid = blockIdx.x;
  int head = ((bid & 7) << 1) | ((bid >> 3) & 1);
  int rsub = bid >> 4;          // [0,40)
  int I = 0, s = 0;
  {
    int acc = 0;
    for (int ii = 0; ii < 16; ++ii) {
      int si = nsplits(ii);
      if (rsub >= acc && rsub < acc + si) { I = ii; s = rsub - acc; }
      acc += si;
    }
  }
  int S_ = nsplits(I);
  int C = (I + 1) * (I + 2) / 2;
  int K0 = 16, K1 = 0;
  {
    int p = 0;
    for (int K = 0; K <= I; ++K) {
      int cost = I - K + 1;
      int seg = ((2 * p + cost) * S_) / (2 * C);
      if (seg == s) { if (K < K0) K0 = K; K1 = K + 1; }
      p += cost;
    }
  }

  const f16* qc = q6 + (size_t)3 * NHSD + (size_t)head * SEQ * DH;   // pre-scaled by dh^-0.5
  const f16* kc = q6 + (size_t)4 * NHSD + (size_t)head * SEQ * DH;
  const f16* vt = q6 + (size_t)5 * NHSD + (size_t)head * DH * SEQ;   // vc transposed [64][2048]
  const f16* t1h = t1T + ((size_t)(head * NTILE + I * (I + 1) / 2) << 14);  // row of t1 tiles for this I
  int tid = threadIdx.x, w = tid >> 6, l = tid & 63, q = l >> 4, c = l & 15;

  // qc_s(I) A-frags for the Sc MFMA
  f16x8 a_qc[2][2];
#pragma unroll
  for (int tr = 0; tr < 2; ++tr)
#pragma unroll
    for (int ks = 0; ks < 2; ++ks)
      a_qc[tr][ks] = *(const f16x8*)(qc + (size_t)(I * 128 + w * 32 + tr * 16 + c) * DH + ks * 32 + q * 8);

  f32x4 su[2][8], oacc[2][4];
  float m_i[2][4], l_i[2][4];
  const f32x4 zf = {0.f, 0.f, 0.f, 0.f};
  for (int tr = 0; tr < 2; ++tr) for (int tv = 0; tv < 4; ++tv) oacc[tr][tv] = zf;
  for (int tr = 0; tr < 2; ++tr) for (int r = 0; r < 4; ++r) { m_i[tr][r] = -INFINITY; l_i[tr][r] = 0.f; }

  for (int K = K0; K < K1; ++K) {
    int offK = 16 * K - (K * (K - 1)) / 2;
#pragma unroll
    for (int tr = 0; tr < 2; ++tr) for (int tc = 0; tc < 8; ++tc) su[tr][tc] = zf;

    for (int J = K; J <= I; ++J) {
      const f16* tt = t1h + ((size_t)J << 14);
      const f16* lt = lkT + ((size_t)(head * NTILE + offK + (J - K)) << 14);
#pragma unroll
      for (int ks = 0; ks < 4; ++ks) {
        f16x8 af[2], bf[8];
#pragma unroll
        for (int tr = 0; tr < 2; ++tr)
          af[tr] = *(const f16x8*)(tt + (size_t)((ks * 8 + w * 2 + tr) * 64 + l) * 8);
#pragma unroll
        for (int tc = 0; tc < 8; ++tc)
          bf[tc] = *(const f16x8*)(lt + (size_t)((ks * 8 + tc) * 64 + l) * 8);
#pragma unroll
        for (int tr = 0; tr < 2; ++tr)
#pragma unroll
          for (int tc = 0; tc < 8; ++tc)
            su[tr][tc] = __builtin_amdgcn_mfma_f32_16x16x32_f16(af[tr], bf[tc], su[tr][tc], 0, 0, 0);
      }
    }

    // scores = Sc - silu(Su)
#pragma unroll
    for (int tr = 0; tr < 2; ++tr)
#pragma unroll
      for (int tc = 0; tc < 8; ++tc)
#pragma unroll
        for (int r = 0; r < 4; ++r) {
          float v = su[tr][tc][r];
          su[tr][tc][r] = -v * __builtin_amdgcn_rcpf(1.f + __expf(-v));
        }
#pragma unroll
    for (int ks = 0; ks < 2; ++ks) {
      f16x8 bk[8];
#pragma unroll
      for (int tc = 0; tc < 8; ++tc)
        bk[tc] = *(const f16x8*)(kc + (size_t)(K * 128 + tc * 16 + c) * DH + ks * 32 + q * 8);
#pragma unroll
      for (int tr = 0; tr < 2; ++tr)
#pragma unroll
        for (int tc = 0; tc < 8; ++tc)
          su[tr][tc] = __builtin_amdgcn_mfma_f32_16x16x32_f16(a_qc[tr][ks], bk[tc], su[tr][tc], 0, 0, 0);
    }
    if (K == I) {   // strict causal mask inside the diagonal block
#pragma unroll
      for (int tr = 0; tr < 2; ++tr)
#pragma unroll
        for (int tc = 0; tc < 8; ++tc)
#pragma unroll
          for (int r = 0; r < 4; ++r) {
            int rg = w * 32 + tr * 16 + q * 4 + r;
            int cg = tc * 16 + c;
            if (cg > rg) su[tr][tc][r] = -INFINITY;
          }
    }
    // online softmax (per-row, shuffle across low-4 lane bits)
#pragma unroll
    for (int tr = 0; tr < 2; ++tr)
#pragma unroll
      for (int r = 0; r < 4; ++r) {
        float mx = su[tr][0][r];
#pragma unroll
        for (int tc = 1; tc < 8; ++tc) mx = fmaxf(mx, su[tr][tc][r]);
        mx = fmaxf(mx, __shfl_xor(mx, 1)); mx = fmaxf(mx, __shfl_xor(mx, 2));
        mx = fmaxf(mx, __shfl_xor(mx, 4)); mx = fmaxf(mx, __shfl_xor(mx, 8));
        float mnew  = fmaxf(m_i[tr][r], mx);
        float alpha = __expf(m_i[tr][r] - mnew);
        float ssum = 0.f;
#pragma unroll
        for (int tc = 0; tc < 8; ++tc) {
          float pp = __expf(su[tr][tc][r] - mnew);
          su[tr][tc][r] = pp;
          ssum += pp;
        }
        ssum += __shfl_xor(ssum, 1); ssum += __shfl_xor(ssum, 2);
        ssum += __shfl_xor(ssum, 4); ssum += __shfl_xor(ssum, 8);
        l_i[tr][r] = l_i[tr][r] * alpha + ssum;
        m_i[tr][r] = mnew;
#pragma unroll
        for (int tv = 0; tv < 4; ++tv) oacc[tr][tv][r] *= alpha;
      }
    // P -> sa (own rows; no barrier)
#pragma unroll
    for (int tr = 0; tr < 2; ++tr)
#pragma unroll
      for (int tc = 0; tc < 8; ++tc)
#pragma unroll
        for (int r = 0; r < 4; ++r) {
          int row = w * 32 + tr * 16 + q * 4 + r;
          int col = tc * 16 + c;
          sa[(row << 7) + (((col >> 3) ^ (row & 15)) << 3) + (col & 7)] = (f16)su[tr][tc][r];
        }
    // PV: A = P (own sa rows), B = vcT from global
#pragma unroll
    for (int ks = 0; ks < 4; ++ks) {
      int ck = ks * 4 + q;
      f16x8 af[2], bv[4];
#pragma unroll
      for (int tr = 0; tr < 2; ++tr)
        af[tr] = *(const f16x8*)(sa + ((w * 32 + tr * 16 + c) << 7) + ((ck ^ c) << 3));
#pragma unroll
      for (int tv = 0; tv < 4; ++tv)
        bv[tv] = *(const f16x8*)(vt + (size_t)(tv * 16 + c) * SEQ + K * 128 + ks * 32 + q * 8);
#pragma unroll
      for (int tr = 0; tr < 2; ++tr)
#pragma unroll
        for (int tv = 0; tv < 4; ++tv)
          oacc[tr][tv] = __builtin_amdgcn_mfma_f32_16x16x32_f16(af[tr], bv[tv], oacc[tr][tv], 0, 0, 0);
    }
  }

  // ---- unnormalized partial, slot = head*40 + rsub ----
  int slot = head * SPLITS_PER_HEAD + rsub;
  f16* po = pO + (size_t)slot * (128 * 64);
  float* pml = pML + (size_t)slot * 256;
  if (c == 0) {
#pragma unroll
    for (int tr = 0; tr < 2; ++tr)
#pragma unroll
      for (int r = 0; r < 4; ++r) {
        int row = w * 32 + tr * 16 + q * 4 + r;
        pml[row] = m_i[tr][r];
        pml[128 + row] = l_i[tr][r];
      }
  }
#pragma unroll
  for (int tr = 0; tr < 2; ++tr)
#pragma unroll
    for (int tv = 0; tv < 4; ++tv)
#pragma unroll
      for (int r = 0; r < 4; ++r) {
        int row = w * 32 + tr * 16 + q * 4 + r;
        int col = tv * 16 + c;
        po[row * 64 + col] = (f16)oacc[tr][tv][r];
      }
}

// ---------------- merge partials -> oh [2048][1024] f16 ----------------
__global__ __launch_bounds__(256) void k_merge(const f16* __restrict__ pO, const float* __restrict__ pML,
                                               f16* __restrict__ oh) {
  int head = blockIdx.x >> 4, I = blockIdx.x & 15;
  int S_ = nsplits(I);
  int base_rsub = 0;
  for (int ii = 0; ii < I; ++ii) base_rsub += nsplits(ii);
  int tid = threadIdx.x;
  int row = tid >> 1, half = tid & 1;
  int base = head * SPLITS_PER_HEAD + base_rsub;
  float m[6], lv[6];
  float mstar = -INFINITY;
#pragma unroll
  for (int s = 0; s < 6; ++s)
    if (s < S_) {
      m[s] = pML[(size_t)(base + s) * 256 + row];
      lv[s] = pML[(size_t)(base + s) * 256 + 128 + row];
      mstar = fmaxf(mstar, m[s]);
    }
  float wt[6];
  float lsum = 0.f;
#pragma unroll
  for (int s = 0; s < 6; ++s)
    if (s < S_) {
      wt[s] = __expf(m[s] - mstar);
      lsum += lv[s] * wt[s];
    }
  float rinv = __builtin_amdgcn_rcpf(lsum);
#pragma unroll
  for (int cc = 0; cc < 32; cc += 8) {
    float acc[8] = {0.f, 0.f, 0.f, 0.f, 0.f, 0.f, 0.f, 0.f};
#pragma unroll
    for (int s = 0; s < 6; ++s)
      if (s < S_) {
        f16x8 v = *(const f16x8*)(pO + (size_t)(base + s) * 8192 + row * 64 + half * 32 + cc);
#pragma unroll
        for (int e = 0; e < 8; ++e) acc[e] += wt[s] * (float)v[e];
      }
    f16x8 o;
#pragma unroll
    for (int e = 0; e < 8; ++e) o[e] = (f16)(acc[e] * rinv);
    *(f16x8*)(oh + (size_t)(I * 128 + row) * DIM + head * 64 + half * 32 + cc) = o;
  }
}

// ---------------- final GEMM: oh[2048,1024] @ WoT[1024,1024]^T -> fp32 out ----------------
__global__ __launch_bounds__(256) void k_gemm_out(const f16* __restrict__ A, const f16* __restrict__ B,
                                                  float* __restrict__ out) {
  __shared__ f16 sa[128 * 72];
  __shared__ f16 sb[128 * 72];
  int bx = blockIdx.x, by = blockIdx.y;
  int tid = threadIdx.x, w = tid >> 6, l = tid & 63, q = l >> 4, c = l & 15;
  f32x4 acc[2][8];
  const f32x4 zf = {0.f, 0.f, 0.f, 0.f};
  for (int i = 0; i < 2; ++i) for (int j = 0; j < 8; ++j) acc[i][j] = zf;
  for (int kt = 0; kt < DIM / 64; ++kt) {
    __syncthreads();
#pragma unroll
    for (int it = 0; it < 4; ++it) {
      int idx = it * 256 + tid; int r = idx >> 3, ch = idx & 7;
      *(float4*)(sa + r * 72 + ch * 8) = *(const float4*)(A + (size_t)(by * 128 + r) * DIM + kt * 64 + ch * 8);
      *(float4*)(sb + r * 72 + ch * 8) = *(const float4*)(B + (size_t)(bx * 128 + r) * DIM + kt * 64 + ch * 8);
    }
    __syncthreads();
#pragma unroll
    for (int ks = 0; ks < 2; ++ks) {
      f16x8 af[2], bf[8];
#pragma unroll
      for (int tr = 0; tr < 2; ++tr) af[tr] = *(const f16x8*)(sa + (w * 32 + tr * 16 + c) * 72 + ks * 32 + q * 8);
#pragma unroll
      for (int tc = 0; tc < 8; ++tc) bf[tc] = *(const f16x8*)(sb + (tc * 16 + c) * 72 + ks * 32 + q * 8);
#pragma unroll
      for (int tr = 0; tr < 2; ++tr)
#pragma unroll
        for (int tc = 0; tc < 8; ++tc)
          acc[tr][tc] = __builtin_amdgcn_mfma_f32_16x16x32_f16(af[tr], bf[tc], acc[tr][tc], 0, 0, 0);
    }
  }
#pragma unroll
  for (int tr = 0; tr < 2; ++tr)
#pragma unroll
    for (int tc = 0; tc < 8; ++tc)
#pragma unroll
      for (int r = 0; r < 4; ++r) {
        int row = by * 128 + w * 32 + tr * 16 + q * 4 + r;
        int col = bx * 128 + tc * 16 + c;
        out[(size_t)row * DIM + col] = acc[tr][tc][r];
      }
}

extern "C" void kernel_launch(void* const* d_in, const int* in_sizes, int n_in,
                              void* d_out, int out_size, void* d_ws, size_t ws_size,
                              hipStream_t stream) {
  const float* x  = (const float*)d_in[0];
  const float* Wq = (const float*)d_in[1];
  const float* Wo = (const float*)d_in[2];
  float* out = (float*)d_out;

  f16* ws = (f16*)d_ws;
  size_t off = 0;
  f16* q6  = ws + off; off += (size_t)6 * NHSD;                        // 25.2 MB
  f16* WqT = ws + off; off += (size_t)NCOLS * DIM;                     // 12.6 MB
  f16* WoT = ws + off; off += (size_t)DIM * DIM;                       // 2.1 MB
  f16* oh  = ws + off; off += (size_t)SEQ * DIM;                       // 4.2 MB
  f16* pO  = ws + off; off += (size_t)NH * SPLITS_PER_HEAD * 128 * 64; // 10.5 MB
  f16* lkT = ws + off; off += (size_t)NH * NTILE * 128 * 128;          // 71.3 MB
  f16* t1T = ws + off; off += (size_t)NH * NTILE * 128 * 128;          // 71.3 MB
  float* pML = (float*)(ws + off); off += (size_t)NH * SPLITS_PER_HEAD * 256 * 2; // 0.66 MB
  // total ~198 MB of workspace (risk: budget known only to be in (126 MB, 316 MB))

  k_tcast<<<dim3(NCOLS / 64, DIM / 64), 256, 0, stream>>>(Wq, WqT, DIM, NCOLS);
  k_tcast<<<dim3(DIM / 64, DIM / 64), 256, 0, stream>>>(Wo, WoT, DIM, DIM);
  k_gemm_qkv<<<dim3(NCOLS / 128, SEQ / 128), 256, 0, stream>>>(x, WqT, q6);
  k_t1lk<<<NH * 272, 256, 0, stream>>>(q6, t1T, lkT);
  k_flash<<<NH * SPLITS_PER_HEAD, 256, 0, stream>>>(q6, t1T, lkT, pO, pML);
  k_merge<<<NH * 16, 256, 0, stream>>>(pO, pML, oh);
  k_gemm_out<<<dim3(DIM / 128, SEQ / 128), 256, 0, stream>>>(oh, WoT, out);
}

// Round 11
// 454.380 us; speedup vs baseline: 3.4379x; 1.0408x over previous
//
#include <hip/hip_runtime.h>
#include <math.h>

typedef _Float16 f16;
typedef _Float16 f16x4 __attribute__((ext_vector_type(4)));
typedef _Float16 f16x8 __attribute__((ext_vector_type(8)));
typedef float f32x4 __attribute__((ext_vector_type(4)));

#define SEQ   2048
#define DIM   1024
#define NH    16
#define DH    64
#define NCOLS 6144
#define NHSD  (NH*SEQ*DH)   /* 2,097,152 elements per qkv sub-tensor */
#define SPLITS_PER_HEAD 40  /* sum of NS[] over I=0..15 */
#define NTILE 136           /* tiles per head per tensor (triangular) */

__device__ __forceinline__ int nsplits(int I) {
  const int NS[16] = {1,1,1,1,1,1,2,2,2,3,3,3,4,4,5,6};
  return NS[I];
}

// ------------- transpose + cast: out[c][r] = (f16) in[r][c], in is R x C -------------
__global__ __launch_bounds__(256) void k_tcast(const float* __restrict__ in, f16* __restrict__ out,
                                               int R, int C) {
  __shared__ f16 t[64 * 66];
  int bc = blockIdx.x, br = blockIdx.y;
  for (int it = 0; it < 16; ++it) {
    int idx = it * 256 + threadIdx.x;
    int r = idx >> 6, c = idx & 63;
    t[r * 66 + c] = (f16)in[(size_t)(br * 64 + r) * C + bc * 64 + c];
  }
  __syncthreads();
  for (int it = 0; it < 16; ++it) {
    int idx = it * 256 + threadIdx.x;
    int oc = idx >> 6, orr = idx & 63;
    out[(size_t)(bc * 64 + oc) * R + br * 64 + orr] = t[orr * 66 + oc];
  }
}

// ---------------- qkv GEMM: x[2048,1024](f32, cast in staging) @ WqT[6144,1024]^T ----------------
__global__ __launch_bounds__(256) void k_gemm_qkv(const float* __restrict__ x, const f16* __restrict__ B,
                                                  f16* __restrict__ q6) {
  __shared__ f16 sa[128 * 72];
  __shared__ f16 sb[128 * 72];
  int bx = blockIdx.x, by = blockIdx.y;
  int tid = threadIdx.x, w = tid >> 6, l = tid & 63, q = l >> 4, c = l & 15;
  f32x4 acc[2][8];
  const f32x4 zf = {0.f, 0.f, 0.f, 0.f};
  for (int i = 0; i < 2; ++i) for (int j = 0; j < 8; ++j) acc[i][j] = zf;

  for (int kt = 0; kt < DIM / 64; ++kt) {
    __syncthreads();
#pragma unroll
    for (int it = 0; it < 4; ++it) {
      int idx = it * 256 + tid; int r = idx >> 3, ch = idx & 7;
      const float* ap = x + (size_t)(by * 128 + r) * DIM + kt * 64 + ch * 8;
      float4 lo = *(const float4*)(ap);
      float4 hi = *(const float4*)(ap + 4);
      f16x8 h;
      h[0] = (f16)lo.x; h[1] = (f16)lo.y; h[2] = (f16)lo.z; h[3] = (f16)lo.w;
      h[4] = (f16)hi.x; h[5] = (f16)hi.y; h[6] = (f16)hi.z; h[7] = (f16)hi.w;
      *(f16x8*)(sa + r * 72 + ch * 8) = h;
      *(float4*)(sb + r * 72 + ch * 8) = *(const float4*)(B + (size_t)(bx * 128 + r) * DIM + kt * 64 + ch * 8);
    }
    __syncthreads();
#pragma unroll
    for (int ks = 0; ks < 2; ++ks) {
      f16x8 af[2], bf[8];
#pragma unroll
      for (int tr = 0; tr < 2; ++tr) af[tr] = *(const f16x8*)(sa + (w * 32 + tr * 16 + c) * 72 + ks * 32 + q * 8);
#pragma unroll
      for (int tc = 0; tc < 8; ++tc) bf[tc] = *(const f16x8*)(sb + (tc * 16 + c) * 72 + ks * 32 + q * 8);
#pragma unroll
      for (int tr = 0; tr < 2; ++tr)
#pragma unroll
        for (int tc = 0; tc < 8; ++tc)
          acc[tr][tc] = __builtin_amdgcn_mfma_f32_16x16x32_f16(af[tr], bf[tc], acc[tr][tc], 0, 0, 0);
    }
  }
  // epilogue: scatter into qu(0) ku(1) vu(2) qc(3) kc(4) vcT(5); scale qu,qc by dh^-0.5
#pragma unroll
  for (int tr = 0; tr < 2; ++tr)
#pragma unroll
    for (int tc = 0; tc < 8; ++tc)
#pragma unroll
      for (int r = 0; r < 4; ++r) {
        int row = by * 128 + w * 32 + tr * 16 + q * 4 + r;
        int col = bx * 128 + tc * 16 + c;
        float v = acc[tr][tc][r];
        int t = col >> 10, head = (col >> 6) & 15, dh = col & 63;
        if (t == 0 || t == 3) v *= 0.125f;
        if (t == 5) q6[(size_t)5 * NHSD + (size_t)(head * DH + dh) * SEQ + row] = (f16)v;
        else        q6[(size_t)t * NHSD + (size_t)(head * SEQ + row) * DH + dh] = (f16)v;
      }
}

// ---------------- t1 + lk tile producer (each distinct tile computed ONCE, stored frag-ordered) ----------------
__global__ __launch_bounds__(256) void k_t1lk(const f16* __restrict__ q6, f16* __restrict__ t1T,
                                              f16* __restrict__ lkT) {
  __shared__ f16 st[128 * 128];
  int head = blockIdx.x / 272;
  int p = blockIdx.x % 272;
  bool is_lk = (p >= 136);
  int RB, CB;        // row-block (i or k), col-block (j)
  f16* dst;
  if (is_lk) {
    int p2 = p - 136;
    int K = 0, off = 0;
    while (off + (16 - K) <= p2) { off += 16 - K; ++K; }
    RB = K; CB = K + (p2 - off);
    dst = lkT + ((size_t)(head * NTILE + p2) << 14);
  } else {
    int I = 0;
    while ((I + 1) * (I + 2) / 2 <= p) ++I;
    RB = I; CB = p - I * (I + 1) / 2;
    dst = t1T + ((size_t)(head * NTILE + p) << 14);
  }
  const f16* Ah = q6 + (size_t)(is_lk ? 0 : 3) * NHSD + (size_t)head * SEQ * DH;  // qu_s / qc_s
  const f16* Bh = q6 + (size_t)(is_lk ? 1 : 2) * NHSD + (size_t)head * SEQ * DH;  // ku / vu
  int tid = threadIdx.x, w = tid >> 6, l = tid & 63, q = l >> 4, c = l & 15;
  const f32x4 zf = {0.f, 0.f, 0.f, 0.f};
  f32x4 tacc[2][8];
  for (int tr = 0; tr < 2; ++tr) for (int tc = 0; tc < 8; ++tc) tacc[tr][tc] = zf;
#pragma unroll
  for (int ks = 0; ks < 2; ++ks) {
    f16x8 aq[2], bf[8];
#pragma unroll
    for (int tr = 0; tr < 2; ++tr)
      aq[tr] = *(const f16x8*)(Ah + (size_t)(RB * 128 + w * 32 + tr * 16 + c) * DH + ks * 32 + q * 8);
#pragma unroll
    for (int tc = 0; tc < 8; ++tc)
      bf[tc] = *(const f16x8*)(Bh + (size_t)(CB * 128 + tc * 16 + c) * DH + ks * 32 + q * 8);
#pragma unroll
    for (int tr = 0; tr < 2; ++tr)
#pragma unroll
      for (int tc = 0; tc < 8; ++tc)
        tacc[tr][tc] = __builtin_amdgcn_mfma_f32_16x16x32_f16(aq[tr], bf[tc], tacc[tr][tc], 0, 0, 0);
  }
  // epilogue: mask (+sigmoid for lk) -> LDS row-major swizzled, own rows
#pragma unroll
  for (int tr = 0; tr < 2; ++tr)
#pragma unroll
    for (int tc = 0; tc < 8; ++tc)
#pragma unroll
      for (int r = 0; r < 4; ++r) {
        int row = w * 32 + tr * 16 + q * 4 + r;
        int col = tc * 16 + c;
        int rg = RB * 128 + row, cg = CB * 128 + col;
        float v = tacc[tr][tc][r];
        f16 ov;
        if (is_lk) ov = (cg > rg) ? (f16)__builtin_amdgcn_rcpf(1.f + __expf(-v)) : (f16)(0.f);
        else       ov = (cg <= rg) ? (f16)v : (f16)(0.f);
        st[(row << 7) + (((col >> 3) ^ (row & 15)) << 3) + (col & 7)] = ov;
      }
  __syncthreads();
  // re-read in frag order, write 16B-coalesced
#pragma unroll
  for (int i = 0; i < 8; ++i) {
    int ch = i * 256 + tid;
    int ks = ch >> 9, rb = (ch >> 6) & 7, ln = ch & 63;
    int qq = ln >> 4, cc = ln & 15;
    int row = rb * 16 + cc, cchunk = ks * 4 + qq;
    f16x8 v = *(const f16x8*)(st + (row << 7) + ((cchunk ^ (row & 15)) << 3));
    *(f16x8*)(dst + (size_t)ch * 8) = v;
  }
}

// ---------------- split-K flash (R11: m97-style async LDS staging of both tiles) ----------------
// R10's J-loop kept 40 frag loads (160 VGPRs if all in flight) in registers -> compiler serialized
// ~4 rounds of load+vmcnt-wait(900cyc) per step = ~11k cyc/step. R11 stages t1+lk tiles into LDS
// via __builtin_amdgcn_global_load_lds width=16 (m97's 517->874 TF lever), frags via ds_read_b128.
// LDS = t1b(32K) + lkb(32K) = 64K -> 2 blocks/CU. P overlays t1b at the K-boundary (barrier-safe).
// Ceiling moves to LDS read BW: 160KB/block-step / ~112 B/cyc/CU ~= 1.4k cyc/step.
// rsub REVERSED so the 128 second-round blocks are the 1..14-step ones (tail shrink).
__global__ __launch_bounds__(256, 1) void k_flash(const f16* __restrict__ q6, const f16* __restrict__ t1T,
                                                  const f16* __restrict__ lkT,
                                                  f16* __restrict__ pO, float* __restrict__ pML) {
  __shared__ f16 t1b[128 * 128];   // staged t1 tile (A-frag chunk order); P overlays after J-loop
  __shared__ f16 lkb[128 * 128];   // staged lk tile (B-frag chunk order)
  int bid = blockIdx.x;
  int head = ((bid & 7) << 1) | ((bid >> 3) & 1);
  int rsub = 39 - (bid >> 4);      // reversed: big splits dispatch first, tiny ones fill the tail round
  int I = 0, s = 0;
  {
    int acc = 0;
    for (int ii = 0; ii < 16; ++ii) {
      int si = nsplits(ii);
      if (rsub >= acc && rsub < acc + si) { I = ii; s = rsub - acc; }
      acc += si;
    }
  }
  int S_ = nsplits(I);
  int C = (I + 1) * (I + 2) / 2;
  int K0 = 16, K1 = 0;
  {
    int p = 0;
    for (int K = 0; K <= I; ++K) {
      int cost = I - K + 1;
      int seg = ((2 * p + cost) * S_) / (2 * C);
      if (seg == s) { if (K < K0) K0 = K; K1 = K + 1; }
      p += cost;
    }
  }

  const f16* qc = q6 + (size_t)3 * NHSD + (size_t)head * SEQ * DH;   // pre-scaled by dh^-0.5
  const f16* kc = q6 + (size_t)4 * NHSD + (size_t)head * SEQ * DH;
  const f16* vt = q6 + (size_t)5 * NHSD + (size_t)head * DH * SEQ;   // vc transposed [64][2048]
  const f16* t1h = t1T + ((size_t)(head * NTILE + I * (I + 1) / 2) << 14);
  int tid = threadIdx.x, w = tid >> 6, l = tid & 63, q = l >> 4, c = l & 15;

  // qc_s(I) A-frags for the Sc MFMA
  f16x8 a_qc[2][2];
#pragma unroll
  for (int tr = 0; tr < 2; ++tr)
#pragma unroll
    for (int ks = 0; ks < 2; ++ks)
      a_qc[tr][ks] = *(const f16x8*)(qc + (size_t)(I * 128 + w * 32 + tr * 16 + c) * DH + ks * 32 + q * 8);

  f32x4 su[2][8], oacc[2][4];
  float m_i[2][4], l_i[2][4];
  const f32x4 zf = {0.f, 0.f, 0.f, 0.f};
  for (int tr = 0; tr < 2; ++tr) for (int tv = 0; tv < 4; ++tv) oacc[tr][tv] = zf;
  for (int tr = 0; tr < 2; ++tr) for (int r = 0; r < 4; ++r) { m_i[tr][r] = -INFINITY; l_i[tr][r] = 0.f; }

  for (int K = K0; K < K1; ++K) {
    int offK = 16 * K - (K * (K - 1)) / 2;
#pragma unroll
    for (int tr = 0; tr < 2; ++tr) for (int tc = 0; tc < 8; ++tc) su[tr][tc] = zf;

    for (int J = K; J <= I; ++J) {
      const f16* tt = t1h + ((size_t)J << 14);
      const f16* lt = lkT + ((size_t)(head * NTILE + offK + (J - K)) << 14);

      __syncthreads();   // WAR: prior buffer reads (Su ds_reads / PV reads of t1b) complete
      // async stage both 32KB tiles: layout is linear in exactly wave-lane order (base + lane*16B)
#pragma unroll
      for (int i = 0; i < 8; ++i) {
        int e = (i * 256 + tid) * 8;
        __builtin_amdgcn_global_load_lds((const __attribute__((address_space(1))) void*)(tt + e),
                                         (__attribute__((address_space(3))) void*)(t1b + e), 16, 0, 0);
        __builtin_amdgcn_global_load_lds((const __attribute__((address_space(1))) void*)(lt + e),
                                         (__attribute__((address_space(3))) void*)(lkb + e), 16, 0, 0);
      }
      __syncthreads();   // RAW: staged tiles visible (barrier drains vmcnt)

#pragma unroll
      for (int ks = 0; ks < 4; ++ks) {
        f16x8 af[2], bf[8];
#pragma unroll
        for (int tr = 0; tr < 2; ++tr)
          af[tr] = *(const f16x8*)(t1b + ((ks * 8 + w * 2 + tr) * 64 + l) * 8);
#pragma unroll
        for (int tc = 0; tc < 8; ++tc)
          bf[tc] = *(const f16x8*)(lkb + ((ks * 8 + tc) * 64 + l) * 8);
#pragma unroll
        for (int tr = 0; tr < 2; ++tr)
#pragma unroll
          for (int tc = 0; tc < 8; ++tc)
            su[tr][tc] = __builtin_amdgcn_mfma_f32_16x16x32_f16(af[tr], bf[tc], su[tr][tc], 0, 0, 0);
      }
    }
    __syncthreads();   // all waves done reading t1b chunks before P overlays it

    // scores = Sc - silu(Su)
#pragma unroll
    for (int tr = 0; tr < 2; ++tr)
#pragma unroll
      for (int tc = 0; tc < 8; ++tc)
#pragma unroll
        for (int r = 0; r < 4; ++r) {
          float v = su[tr][tc][r];
          su[tr][tc][r] = -v * __builtin_amdgcn_rcpf(1.f + __expf(-v));
        }
#pragma unroll
    for (int ks = 0; ks < 2; ++ks) {
      f16x8 bk[8];
#pragma unroll
      for (int tc = 0; tc < 8; ++tc)
        bk[tc] = *(const f16x8*)(kc + (size_t)(K * 128 + tc * 16 + c) * DH + ks * 32 + q * 8);
#pragma unroll
      for (int tr = 0; tr < 2; ++tr)
#pragma unroll
        for (int tc = 0; tc < 8; ++tc)
          su[tr][tc] = __builtin_amdgcn_mfma_f32_16x16x32_f16(a_qc[tr][ks], bk[tc], su[tr][tc], 0, 0, 0);
    }
    if (K == I) {   // strict causal mask inside the diagonal block
#pragma unroll
      for (int tr = 0; tr < 2; ++tr)
#pragma unroll
        for (int tc = 0; tc < 8; ++tc)
#pragma unroll
          for (int r = 0; r < 4; ++r) {
            int rg = w * 32 + tr * 16 + q * 4 + r;
            int cg = tc * 16 + c;
            if (cg > rg) su[tr][tc][r] = -INFINITY;
          }
    }
    // online softmax (per-row, shuffle across low-4 lane bits)
#pragma unroll
    for (int tr = 0; tr < 2; ++tr)
#pragma unroll
      for (int r = 0; r < 4; ++r) {
        float mx = su[tr][0][r];
#pragma unroll
        for (int tc = 1; tc < 8; ++tc) mx = fmaxf(mx, su[tr][tc][r]);
        mx = fmaxf(mx, __shfl_xor(mx, 1)); mx = fmaxf(mx, __shfl_xor(mx, 2));
        mx = fmaxf(mx, __shfl_xor(mx, 4)); mx = fmaxf(mx, __shfl_xor(mx, 8));
        float mnew  = fmaxf(m_i[tr][r], mx);
        float alpha = __expf(m_i[tr][r] - mnew);
        float ssum = 0.f;
#pragma unroll
        for (int tc = 0; tc < 8; ++tc) {
          float pp = __expf(su[tr][tc][r] - mnew);
          su[tr][tc][r] = pp;
          ssum += pp;
        }
        ssum += __shfl_xor(ssum, 1); ssum += __shfl_xor(ssum, 2);
        ssum += __shfl_xor(ssum, 4); ssum += __shfl_xor(ssum, 8);
        l_i[tr][r] = l_i[tr][r] * alpha + ssum;
        m_i[tr][r] = mnew;
#pragma unroll
        for (int tv = 0; tv < 4; ++tv) oacc[tr][tv][r] *= alpha;
      }
    // P -> t1b overlay (row-swizzled; own 32-row region of the buffer, disjoint per wave)
#pragma unroll
    for (int tr = 0; tr < 2; ++tr)
#pragma unroll
      for (int tc = 0; tc < 8; ++tc)
#pragma unroll
        for (int r = 0; r < 4; ++r) {
          int row = w * 32 + tr * 16 + q * 4 + r;
          int col = tc * 16 + c;
          t1b[(row << 7) + (((col >> 3) ^ (row & 15)) << 3) + (col & 7)] = (f16)su[tr][tc][r];
        }
    // PV: A = P (own t1b rows), B = vcT from global
#pragma unroll
    for (int ks = 0; ks < 4; ++ks) {
      int ck = ks * 4 + q;
      f16x8 af[2], bv[4];
#pragma unroll
      for (int tr = 0; tr < 2; ++tr)
        af[tr] = *(const f16x8*)(t1b + ((w * 32 + tr * 16 + c) << 7) + ((ck ^ c) << 3));
#pragma unroll
      for (int tv = 0; tv < 4; ++tv)
        bv[tv] = *(const f16x8*)(vt + (size_t)(tv * 16 + c) * SEQ + K * 128 + ks * 32 + q * 8);
#pragma unroll
      for (int tr = 0; tr < 2; ++tr)
#pragma unroll
        for (int tv = 0; tv < 4; ++tv)
          oacc[tr][tv] = __builtin_amdgcn_mfma_f32_16x16x32_f16(af[tr], bv[tv], oacc[tr][tv], 0, 0, 0);
    }
  }

  // ---- unnormalized partial, slot = head*40 + rsub ----
  int slot = head * SPLITS_PER_HEAD + rsub;
  f16* po = pO + (size_t)slot * (128 * 64);
  float* pml = pML + (size_t)slot * 256;
  if (c == 0) {
#pragma unroll
    for (int tr = 0; tr < 2; ++tr)
#pragma unroll
      for (int r = 0; r < 4; ++r) {
        int row = w * 32 + tr * 16 + q * 4 + r;
        pml[row] = m_i[tr][r];
        pml[128 + row] = l_i[tr][r];
      }
  }
#pragma unroll
  for (int tr = 0; tr < 2; ++tr)
#pragma unroll
    for (int tv = 0; tv < 4; ++tv)
#pragma unroll
      for (int r = 0; r < 4; ++r) {
        int row = w * 32 + tr * 16 + q * 4 + r;
        int col = tv * 16 + c;
        po[row * 64 + col] = (f16)oacc[tr][tv][r];
      }
}

// ---------------- merge partials -> oh [2048][1024] f16 ----------------
__global__ __launch_bounds__(256) void k_merge(const f16* __restrict__ pO, const float* __restrict__ pML,
                                               f16* __restrict__ oh) {
  int head = blockIdx.x >> 4, I = blockIdx.x & 15;
  int S_ = nsplits(I);
  int base_rsub = 0;
  for (int ii = 0; ii < I; ++ii) base_rsub += nsplits(ii);
  int tid = threadIdx.x;
  int row = tid >> 1, half = tid & 1;
  int base = head * SPLITS_PER_HEAD + base_rsub;
  float m[6], lv[6];
  float mstar = -INFINITY;
#pragma unroll
  for (int s = 0; s < 6; ++s)
    if (s < S_) {
      m[s] = pML[(size_t)(base + s) * 256 + row];
      lv[s] = pML[(size_t)(base + s) * 256 + 128 + row];
      mstar = fmaxf(mstar, m[s]);
    }
  float wt[6];
  float lsum = 0.f;
#pragma unroll
  for (int s = 0; s < 6; ++s)
    if (s < S_) {
      wt[s] = __expf(m[s] - mstar);
      lsum += lv[s] * wt[s];
    }
  float rinv = __builtin_amdgcn_rcpf(lsum);
#pragma unroll
  for (int cc = 0; cc < 32; cc += 8) {
    float acc[8] = {0.f, 0.f, 0.f, 0.f, 0.f, 0.f, 0.f, 0.f};
#pragma unroll
    for (int s = 0; s < 6; ++s)
      if (s < S_) {
        f16x8 v = *(const f16x8*)(pO + (size_t)(base + s) * 8192 + row * 64 + half * 32 + cc);
#pragma unroll
        for (int e = 0; e < 8; ++e) acc[e] += wt[s] * (float)v[e];
      }
    f16x8 o;
#pragma unroll
    for (int e = 0; e < 8; ++e) o[e] = (f16)(acc[e] * rinv);
    *(f16x8*)(oh + (size_t)(I * 128 + row) * DIM + head * 64 + half * 32 + cc) = o;
  }
}

// ---------------- final GEMM: oh[2048,1024] @ WoT[1024,1024]^T -> fp32 out ----------------
__global__ __launch_bounds__(256) void k_gemm_out(const f16* __restrict__ A, const f16* __restrict__ B,
                                                  float* __restrict__ out) {
  __shared__ f16 sa[128 * 72];
  __shared__ f16 sb[128 * 72];
  int bx = blockIdx.x, by = blockIdx.y;
  int tid = threadIdx.x, w = tid >> 6, l = tid & 63, q = l >> 4, c = l & 15;
  f32x4 acc[2][8];
  const f32x4 zf = {0.f, 0.f, 0.f, 0.f};
  for (int i = 0; i < 2; ++i) for (int j = 0; j < 8; ++j) acc[i][j] = zf;
  for (int kt = 0; kt < DIM / 64; ++kt) {
    __syncthreads();
#pragma unroll
    for (int it = 0; it < 4; ++it) {
      int idx = it * 256 + tid; int r = idx >> 3, ch = idx & 7;
      *(float4*)(sa + r * 72 + ch * 8) = *(const float4*)(A + (size_t)(by * 128 + r) * DIM + kt * 64 + ch * 8);
      *(float4*)(sb + r * 72 + ch * 8) = *(const float4*)(B + (size_t)(bx * 128 + r) * DIM + kt * 64 + ch * 8);
    }
    __syncthreads();
#pragma unroll
    for (int ks = 0; ks < 2; ++ks) {
      f16x8 af[2], bf[8];
#pragma unroll
      for (int tr = 0; tr < 2; ++tr) af[tr] = *(const f16x8*)(sa + (w * 32 + tr * 16 + c) * 72 + ks * 32 + q * 8);
#pragma unroll
      for (int tc = 0; tc < 8; ++tc) bf[tc] = *(const f16x8*)(sb + (tc * 16 + c) * 72 + ks * 32 + q * 8);
#pragma unroll
      for (int tr = 0; tr < 2; ++tr)
#pragma unroll
        for (int tc = 0; tc < 8; ++tc)
          acc[tr][tc] = __builtin_amdgcn_mfma_f32_16x16x32_f16(af[tr], bf[tc], acc[tr][tc], 0, 0, 0);
    }
  }
#pragma unroll
  for (int tr = 0; tr < 2; ++tr)
#pragma unroll
    for (int tc = 0; tc < 8; ++tc)
#pragma unroll
      for (int r = 0; r < 4; ++r) {
        int row = by * 128 + w * 32 + tr * 16 + q * 4 + r;
        int col = bx * 128 + tc * 16 + c;
        out[(size_t)row * DIM + col] = acc[tr][tc][r];
      }
}

extern "C" void kernel_launch(void* const* d_in, const int* in_sizes, int n_in,
                              void* d_out, int out_size, void* d_ws, size_t ws_size,
                              hipStream_t stream) {
  const float* x  = (const float*)d_in[0];
  const float* Wq = (const float*)d_in[1];
  const float* Wo = (const float*)d_in[2];
  float* out = (float*)d_out;

  f16* ws = (f16*)d_ws;
  size_t off = 0;
  f16* q6  = ws + off; off += (size_t)6 * NHSD;                        // 25.2 MB
  f16* WqT = ws + off; off += (size_t)NCOLS * DIM;                     // 12.6 MB
  f16* WoT = ws + off; off += (size_t)DIM * DIM;                       // 2.1 MB
  f16* oh  = ws + off; off += (size_t)SEQ * DIM;                       // 4.2 MB
  f16* pO  = ws + off; off += (size_t)NH * SPLITS_PER_HEAD * 128 * 64; // 10.5 MB
  f16* lkT = ws + off; off += (size_t)NH * NTILE * 128 * 128;          // 71.3 MB
  f16* t1T = ws + off; off += (size_t)NH * NTILE * 128 * 128;          // 71.3 MB
  float* pML = (float*)(ws + off); off += (size_t)NH * SPLITS_PER_HEAD * 256 * 2; // 0.66 MB
  // total ~198 MB of workspace (known-good: <=198 worked in R10)

  k_tcast<<<dim3(NCOLS / 64, DIM / 64), 256, 0, stream>>>(Wq, WqT, DIM, NCOLS);
  k_tcast<<<dim3(DIM / 64, DIM / 64), 256, 0, stream>>>(Wo, WoT, DIM, DIM);
  k_gemm_qkv<<<dim3(NCOLS / 128, SEQ / 128), 256, 0, stream>>>(x, WqT, q6);
  k_t1lk<<<NH * 272, 256, 0, stream>>>(q6, t1T, lkT);
  k_flash<<<NH * SPLITS_PER_HEAD, 256, 0, stream>>>(q6, t1T, lkT, pO, pML);
  k_merge<<<NH * 16, 256, 0, stream>>>(pO, pML, oh);
  k_gemm_out<<<dim3(DIM / 128, SEQ / 128), 256, 0, stream>>>(oh, WoT, out);
}